// Round 1
// baseline (3038.370 us; speedup 1.0000x reference)
//
#include <hip/hip_runtime.h>

// ---------------- problem constants ----------------
constexpr int Nn = 50000;
constexpr int Ee = 800000;
constexpr int INCH = 64;
constexpr int HH = 128;
constexpr int KE = 288;     // 258 padded to 288 (9 chunks of 32)
constexpr int EIN_STR = 296; // LDS row stride (bf16) for edge_in, padded for banks
constexpr int EF_STR  = 136; // LDS row stride (bf16) for ef buffers

typedef short s8v __attribute__((ext_vector_type(8)));
typedef float f4v __attribute__((ext_vector_type(4)));

__device__ __forceinline__ ushort f2bf(float f) {
    uint u = __float_as_uint(f);
    uint r = (u + 0x7FFFu + ((u >> 16) & 1u)) >> 16;
    return (ushort)r;
}
__device__ __forceinline__ float bf2f(ushort s) {
    return __uint_as_float(((uint)s) << 16);
}
__device__ __forceinline__ float silu_f(float x) {
    return x * __fdividef(1.0f, 1.0f + __expf(-x));
}

// ---------------- weight pre-swizzle into MFMA B-fragment order ----------------
// dst layout per weight: [kc][t][lane][j] ; element = W[kc*32 + (lane>>4)*8 + j][t*16 + (lane&15)]
// eW1: K=258 padded to 288 (9 kc); eW2/cW1: K=128 (4 kc). All N=128 (8 t-tiles).
__global__ void __launch_bounds__(256) k_swz(
    const float* __restrict__ eW1, const float* __restrict__ eW2, const float* __restrict__ cW1,
    ushort* __restrict__ o1, ushort* __restrict__ o2, ushort* __restrict__ o3)
{
    int gid = blockIdx.x * 256 + threadIdx.x; // total 4*69632 = 278528, exact grid
    int l = gid / 69632, r = gid % 69632;
    const float* src; ushort* dst; int Ks, idx;
    if (r < 36864)      { src = eW1 + (size_t)l * 258 * 128; dst = o1 + l * 36864; Ks = 258; idx = r; }
    else if (r < 53248) { src = eW2 + (size_t)l * 128 * 128; dst = o2 + l * 16384; Ks = 128; idx = r - 36864; }
    else                { src = cW1 + (size_t)l * 128 * 128; dst = o3 + l * 16384; Ks = 128; idx = r - 53248; }
    int fb = idx >> 9, rem = idx & 511;
    int lane = rem >> 3, jj = rem & 7;
    int kc = fb >> 3, t = fb & 7;
    int k = kc * 32 + ((lane >> 4) << 3) + jj;
    int n = t * 16 + (lane & 15);
    float v = (k < Ks) ? src[k * 128 + n] : 0.0f;
    dst[idx] = f2bf(v);
}

// ---------------- incoming-edge counts ----------------
__global__ void __launch_bounds__(256) k_count(const int* __restrict__ eidx, float* __restrict__ counts)
{
    int e = blockIdx.x * 256 + threadIdx.x; // grid exact
    unsafeAtomicAdd(&counts[eidx[Ee + e]], 1.0f);
}

// ---------------- input embedding + coord copy ----------------
__global__ void __launch_bounds__(128) k_emb(
    const float* __restrict__ h_in, const float* __restrict__ coords,
    const float* __restrict__ W, const float* __restrict__ b,
    float* __restrict__ hbuf, ushort* __restrict__ hbf, float* __restrict__ cbuf)
{
    __shared__ float sh[64];
    int n = blockIdx.x, j = threadIdx.x;
    if (j < 64) sh[j] = h_in[(size_t)n * 64 + j];
    __syncthreads();
    float acc = b[j];
    #pragma unroll 8
    for (int k = 0; k < 64; k++) acc += sh[k] * W[k * 128 + j];
    hbuf[(size_t)n * 128 + j] = acc;
    hbf[(size_t)n * 128 + j] = f2bf(acc);
    if (j < 3) cbuf[n * 3 + j] = coords[n * 3 + j];
}

// ---------------- fused edge MLP + atomic aggregation (MFMA bf16) ----------------
__global__ void __launch_bounds__(256, 2) k_edge(
    const ushort* __restrict__ hbf, const float* __restrict__ cbuf,
    const float* __restrict__ edge_attr, const int* __restrict__ eidx,
    const ushort* __restrict__ w1s, const float* __restrict__ b1,
    const ushort* __restrict__ w2s, const float* __restrict__ b2,
    const ushort* __restrict__ cw1s, const float* __restrict__ cb1,
    const float* __restrict__ cwc,
    float* __restrict__ agg_feat, float* __restrict__ agg_coord)
{
    __shared__ alignas(16) ushort s_ein[64 * EIN_STR]; // 37.9 KB
    __shared__ alignas(16) ushort s_efa[64 * EF_STR];  // 17.4 KB
    __shared__ alignas(16) ushort s_efb[64 * EF_STR];  // 17.4 KB
    __shared__ int   s_col[64];
    __shared__ float s_cd[64 * 3];

    const int tid = threadIdx.x;
    const int eb = blockIdx.x * 64;

    // --- edge metadata: coord_diff, dist, edge_attr, K-pad zeros ---
    if (tid < 64) {
        int e = eb + tid;
        int rw = eidx[e], cl = eidx[Ee + e];
        s_col[tid] = cl;
        float d0 = cbuf[rw * 3 + 0] - cbuf[cl * 3 + 0];
        float d1 = cbuf[rw * 3 + 1] - cbuf[cl * 3 + 1];
        float d2 = cbuf[rw * 3 + 2] - cbuf[cl * 3 + 2];
        s_cd[tid * 3 + 0] = d0; s_cd[tid * 3 + 1] = d1; s_cd[tid * 3 + 2] = d2;
        float dist = d0 * d0 + d1 * d1 + d2 * d2;
        s_ein[tid * EIN_STR + 256] = f2bf(dist);
        s_ein[tid * EIN_STR + 257] = f2bf(edge_attr[e]);
        uint* zp = (uint*)(s_ein + tid * EIN_STR + 258); // 258..287 zero (15 dwords)
        #pragma unroll
        for (int z = 0; z < 15; z++) zp[z] = 0;
    }
    // --- gather h[col] (k<128) and h[row] (128..255) as bf16, 16B chunks ---
    #pragma unroll
    for (int i = 0; i < 8; i++) {
        int idx = i * 256 + tid;
        int e = idx >> 5, ch = idx & 31;
        int node = (ch < 16) ? eidx[Ee + eb + e] : eidx[eb + e];
        uint4 v = *(const uint4*)(hbf + (size_t)node * 128 + (ch & 15) * 8);
        *(uint4*)(s_ein + e * EIN_STR + ch * 8) = v;
    }
    __syncthreads();

    const int lane = tid & 63, wave = tid >> 6;
    const int m = lane & 15, quad = lane >> 4;
    const int wrow = wave * 16; // this wave's 16 edges; no cross-wave deps below

    // ---- GEMM1: [16,288] @ [288,128] ----
    {
        f4v acc[8];
        #pragma unroll
        for (int t = 0; t < 8; t++) acc[t] = (f4v){0.f, 0.f, 0.f, 0.f};
        const ushort* aRow = s_ein + (wrow + m) * EIN_STR + quad * 8;
        const ushort* bBase = w1s + (size_t)lane * 8;
        #pragma unroll
        for (int kc = 0; kc < 9; kc++) {
            s8v af = *(const s8v*)(aRow + kc * 32);
            const ushort* bp = bBase + kc * 4096;
            #pragma unroll
            for (int t = 0; t < 8; t++) {
                s8v bfr = *(const s8v*)(bp + t * 512);
                acc[t] = __builtin_amdgcn_mfma_f32_16x16x32_bf16(af, bfr, acc[t], 0, 0, 0);
            }
        }
        #pragma unroll
        for (int t = 0; t < 8; t++) {
            int col = t * 16 + m;
            float bias = b1[col];
            #pragma unroll
            for (int r = 0; r < 4; r++) {
                int row = wrow + quad * 4 + r;
                s_efa[row * EF_STR + col] = f2bf(silu_f(acc[t][r] + bias));
            }
        }
    }
    __syncthreads();

    // ---- GEMM2: [16,128] @ [128,128] ----
    {
        f4v acc[8];
        #pragma unroll
        for (int t = 0; t < 8; t++) acc[t] = (f4v){0.f, 0.f, 0.f, 0.f};
        const ushort* aRow = s_efa + (wrow + m) * EF_STR + quad * 8;
        const ushort* bBase = w2s + (size_t)lane * 8;
        #pragma unroll
        for (int kc = 0; kc < 4; kc++) {
            s8v af = *(const s8v*)(aRow + kc * 32);
            const ushort* bp = bBase + kc * 4096;
            #pragma unroll
            for (int t = 0; t < 8; t++) {
                s8v bfr = *(const s8v*)(bp + t * 512);
                acc[t] = __builtin_amdgcn_mfma_f32_16x16x32_bf16(af, bfr, acc[t], 0, 0, 0);
            }
        }
        #pragma unroll
        for (int t = 0; t < 8; t++) {
            int col = t * 16 + m;
            float bias = b2[col];
            #pragma unroll
            for (int r = 0; r < 4; r++) {
                int row = wrow + quad * 4 + r;
                s_efb[row * EF_STR + col] = f2bf(silu_f(acc[t][r] + bias));
            }
        }
    }
    __syncthreads();

    // ---- coord gate: cw = silu(ef @ cW1 + cb1) @ cWc ----
    {
        f4v acc[8];
        #pragma unroll
        for (int t = 0; t < 8; t++) acc[t] = (f4v){0.f, 0.f, 0.f, 0.f};
        const ushort* aRow = s_efb + (wrow + m) * EF_STR + quad * 8;
        const ushort* bBase = cw1s + (size_t)lane * 8;
        #pragma unroll
        for (int kc = 0; kc < 4; kc++) {
            s8v af = *(const s8v*)(aRow + kc * 32);
            const ushort* bp = bBase + kc * 4096;
            #pragma unroll
            for (int t = 0; t < 8; t++) {
                s8v bfr = *(const s8v*)(bp + t * 512);
                acc[t] = __builtin_amdgcn_mfma_f32_16x16x32_bf16(af, bfr, acc[t], 0, 0, 0);
            }
        }
        float p0 = 0.f, p1 = 0.f, p2 = 0.f, p3 = 0.f;
        #pragma unroll
        for (int t = 0; t < 8; t++) {
            int col = t * 16 + m;
            float bias = cb1[col];
            float wc = cwc[col];
            p0 += silu_f(acc[t][0] + bias) * wc;
            p1 += silu_f(acc[t][1] + bias) * wc;
            p2 += silu_f(acc[t][2] + bias) * wc;
            p3 += silu_f(acc[t][3] + bias) * wc;
        }
        // reduce across the 16 lanes of this quad (bits 0..3 of lane)
        #pragma unroll
        for (int off = 1; off < 16; off <<= 1) {
            p0 += __shfl_xor(p0, off, 64);
            p1 += __shfl_xor(p1, off, 64);
            p2 += __shfl_xor(p2, off, 64);
            p3 += __shfl_xor(p3, off, 64);
        }
        // lanes m<12 scatter coord updates: m = d*4 + r
        if (m < 12) {
            int r = m & 3, d = m >> 2;
            float cw = (r == 0) ? p0 : (r == 1) ? p1 : (r == 2) ? p2 : p3;
            int er = wrow + quad * 4 + r;
            int cn = s_col[er];
            unsafeAtomicAdd(&agg_coord[cn * 3 + d], s_cd[er * 3 + d] * cw);
        }
    }

    // ---- feature aggregation (wave-private rows, no barrier needed) ----
    #pragma unroll
    for (int i = 0; i < 32; i++) {
        int e = wrow + (i >> 1);
        int j = (i & 1) * 64 + lane;
        float v = bf2f(s_efb[e * EF_STR + j]);
        unsafeAtomicAdd(&agg_feat[(size_t)s_col[e] * 128 + j], v);
    }
}

// ---------------- node update (fp32 register-tiled) ----------------
__global__ void __launch_bounds__(256, 2) k_node(
    float* __restrict__ hbuf, ushort* __restrict__ hbf, float* __restrict__ cbuf,
    const float* __restrict__ agg_feat, const float* __restrict__ agg_coord,
    const float* __restrict__ counts,
    const float* __restrict__ w1, const float* __restrict__ b1,
    const float* __restrict__ w2, const float* __restrict__ b2)
{
    __shared__ alignas(16) float s_a[64 * 36];
    __shared__ alignas(16) float s_t1[64 * 132];
    const int tid = threadIdx.x;
    const int tx = tid & 31, ty = tid >> 5;
    const int nb = blockIdx.x * 64;

    float acc[8][4];
    #pragma unroll
    for (int e = 0; e < 8; e++)
        #pragma unroll
        for (int j = 0; j < 4; j++) acc[e][j] = 0.f;

    // GEMM1: node_in = [h | agg_feat], K=256
    for (int kc = 0; kc < 8; kc++) {
        #pragma unroll
        for (int ii = 0; ii < 2; ii++) {
            int idx4 = ii * 256 + tid;
            int e = idx4 >> 3, seg = idx4 & 7;
            int node = nb + e;
            int k = kc * 32 + seg * 4;
            float4 v = make_float4(0.f, 0.f, 0.f, 0.f);
            if (node < Nn)
                v = (k < 128) ? *(const float4*)(hbuf + (size_t)node * 128 + k)
                              : *(const float4*)(agg_feat + (size_t)node * 128 + (k - 128));
            *(float4*)(s_a + e * 36 + seg * 4) = v;
        }
        __syncthreads();
        #pragma unroll
        for (int kk = 0; kk < 8; kk++) {
            float bb[4][4];
            #pragma unroll
            for (int i = 0; i < 4; i++)
                *(float4*)bb[i] = *(const float4*)(w1 + (size_t)(kc * 32 + kk * 4 + i) * 128 + tx * 4);
            #pragma unroll
            for (int e2 = 0; e2 < 8; e2++) {
                float aa[4];
                *(float4*)aa = *(const float4*)(s_a + (ty * 8 + e2) * 36 + kk * 4);
                #pragma unroll
                for (int i = 0; i < 4; i++)
                    #pragma unroll
                    for (int j = 0; j < 4; j++)
                        acc[e2][j] += aa[i] * bb[i][j];
            }
        }
        __syncthreads();
    }

    // coords += agg_coord / max(counts,1)
    if (tid < 64) {
        int n = nb + tid;
        if (n < Nn) {
            float c = counts[n]; c = (c < 1.0f) ? 1.0f : c;
            float inv = __fdividef(1.0f, c);
            cbuf[n * 3 + 0] += agg_coord[n * 3 + 0] * inv;
            cbuf[n * 3 + 1] += agg_coord[n * 3 + 1] * inv;
            cbuf[n * 3 + 2] += agg_coord[n * 3 + 2] * inv;
        }
    }

    // t1 = silu(acc + b1)
    float bb1[4]; *(float4*)bb1 = *(const float4*)(b1 + tx * 4);
    #pragma unroll
    for (int e2 = 0; e2 < 8; e2++) {
        float4 o;
        o.x = silu_f(acc[e2][0] + bb1[0]);
        o.y = silu_f(acc[e2][1] + bb1[1]);
        o.z = silu_f(acc[e2][2] + bb1[2]);
        o.w = silu_f(acc[e2][3] + bb1[3]);
        *(float4*)(s_t1 + (ty * 8 + e2) * 132 + tx * 4) = o;
    }
    __syncthreads();

    // GEMM2: K=128
    float acc2[8][4];
    #pragma unroll
    for (int e = 0; e < 8; e++)
        #pragma unroll
        for (int j = 0; j < 4; j++) acc2[e][j] = 0.f;
    #pragma unroll 4
    for (int kk = 0; kk < 32; kk++) {
        float bb[4][4];
        #pragma unroll
        for (int i = 0; i < 4; i++)
            *(float4*)bb[i] = *(const float4*)(w2 + (size_t)(kk * 4 + i) * 128 + tx * 4);
        #pragma unroll
        for (int e2 = 0; e2 < 8; e2++) {
            float aa[4];
            *(float4*)aa = *(const float4*)(s_t1 + (ty * 8 + e2) * 132 + kk * 4);
            #pragma unroll
            for (int i = 0; i < 4; i++)
                #pragma unroll
                for (int j = 0; j < 4; j++)
                    acc2[e2][j] += aa[i] * bb[i][j];
        }
    }

    // h += upd; refresh bf16 mirror
    float bb2[4]; *(float4*)bb2 = *(const float4*)(b2 + tx * 4);
    #pragma unroll
    for (int e2 = 0; e2 < 8; e2++) {
        int node = nb + ty * 8 + e2;
        if (node < Nn) {
            float4 old = *(const float4*)(hbuf + (size_t)node * 128 + tx * 4);
            float v0 = old.x + acc2[e2][0] + bb2[0];
            float v1 = old.y + acc2[e2][1] + bb2[1];
            float v2 = old.z + acc2[e2][2] + bb2[2];
            float v3 = old.w + acc2[e2][3] + bb2[3];
            float4 nv = make_float4(v0, v1, v2, v3);
            *(float4*)(hbuf + (size_t)node * 128 + tx * 4) = nv;
            ushort4 nb16; nb16.x = f2bf(v0); nb16.y = f2bf(v1); nb16.z = f2bf(v2); nb16.w = f2bf(v3);
            *(ushort4*)(hbf + (size_t)node * 128 + tx * 4) = nb16;
        }
    }
}

// ---------------- output embedding + coords out ----------------
__global__ void __launch_bounds__(256) k_emb_out(
    const float* __restrict__ hbuf, const float* __restrict__ cbuf,
    const float* __restrict__ W, const float* __restrict__ b, float* __restrict__ out)
{
    __shared__ float sh[256];
    int tid = threadIdx.x;
    int local = tid >> 7, j = tid & 127;
    int n = blockIdx.x * 2 + local; // 25000*2 == N exact
    sh[tid] = hbuf[(size_t)n * 128 + j];
    __syncthreads();
    float acc = b[j];
    #pragma unroll 8
    for (int k = 0; k < 128; k++) acc += sh[local * 128 + k] * W[k * 128 + j];
    out[(size_t)n * 128 + j] = acc;
    if (tid < 6) {
        int n2 = blockIdx.x * 2 + tid / 3, d = tid - (tid / 3) * 3;
        out[(size_t)Nn * 128 + n2 * 3 + d] = cbuf[n2 * 3 + d];
    }
}

// ---------------- host launcher ----------------
extern "C" void kernel_launch(void* const* d_in, const int* in_sizes, int n_in,
                              void* d_out, int out_size, void* d_ws, size_t ws_size,
                              hipStream_t stream)
{
    const float* h_in      = (const float*)d_in[0];
    const float* coords    = (const float*)d_in[1];
    const float* edge_attr = (const float*)d_in[2];
    const float* emb_in_W  = (const float*)d_in[3];
    const float* emb_in_b  = (const float*)d_in[4];
    const float* emb_out_W = (const float*)d_in[5];
    const float* emb_out_b = (const float*)d_in[6];
    const float* eW1 = (const float*)d_in[7];
    const float* eb1 = (const float*)d_in[8];
    const float* eW2 = (const float*)d_in[9];
    const float* eb2 = (const float*)d_in[10];
    const float* cW1 = (const float*)d_in[11];
    const float* cb1 = (const float*)d_in[12];
    const float* cWc = (const float*)d_in[13];
    const float* nW1 = (const float*)d_in[14];
    const float* nb1 = (const float*)d_in[15];
    const float* nW2 = (const float*)d_in[16];
    const float* nb2 = (const float*)d_in[17];
    const int*  eidx = (const int*)d_in[18];

    size_t off = 0;
    char* base = (char*)d_ws;
    auto alloc = [&](size_t bytes) -> char* {
        char* p = base + off;
        off += (bytes + 255) & ~(size_t)255;
        return p;
    };
    float*  hbuf      = (float*)alloc((size_t)Nn * 128 * 4);
    ushort* hbf       = (ushort*)alloc((size_t)Nn * 128 * 2);
    float*  cbuf      = (float*)alloc((size_t)Nn * 3 * 4);
    float*  counts    = (float*)alloc((size_t)Nn * 4);
    float*  agg_feat  = (float*)alloc((size_t)Nn * 128 * 4);
    float*  agg_coord = (float*)alloc((size_t)Nn * 3 * 4);
    ushort* eW1s      = (ushort*)alloc((size_t)4 * 36864 * 2);
    ushort* eW2s      = (ushort*)alloc((size_t)4 * 16384 * 2);
    ushort* cW1s      = (ushort*)alloc((size_t)4 * 16384 * 2);

    k_swz<<<1088, 256, 0, stream>>>(eW1, eW2, cW1, eW1s, eW2s, cW1s);
    hipMemsetAsync(counts, 0, (size_t)Nn * 4, stream);
    k_count<<<Ee / 256, 256, 0, stream>>>(eidx, counts);
    k_emb<<<Nn, 128, 0, stream>>>(h_in, coords, emb_in_W, emb_in_b, hbuf, hbf, cbuf);

    for (int l = 0; l < 4; l++) {
        hipMemsetAsync(agg_feat, 0, (size_t)Nn * 128 * 4, stream);
        hipMemsetAsync(agg_coord, 0, (size_t)Nn * 3 * 4, stream);
        k_edge<<<Ee / 64, 256, 0, stream>>>(
            hbf, cbuf, edge_attr, eidx,
            eW1s + (size_t)l * 36864, eb1 + l * 128,
            eW2s + (size_t)l * 16384, eb2 + l * 128,
            cW1s + (size_t)l * 16384, cb1 + l * 128,
            cWc + l * 128,
            agg_feat, agg_coord);
        k_node<<<(Nn + 63) / 64, 256, 0, stream>>>(
            hbuf, hbf, cbuf, agg_feat, agg_coord, counts,
            nW1 + (size_t)l * 256 * 128, nb1 + l * 128,
            nW2 + (size_t)l * 128 * 128, nb2 + l * 128);
    }
    k_emb_out<<<Nn / 2, 256, 0, stream>>>(hbuf, cbuf, emb_out_W, emb_out_b, (float*)d_out);
}

// Round 2
// 2535.398 us; speedup vs baseline: 1.1984x; 1.1984x over previous
//
#include <hip/hip_runtime.h>

// ---------------- problem constants ----------------
constexpr int Nn = 50000;
constexpr int Ee = 800000;
constexpr int EIN_STR = 296; // LDS row stride (bf16) for edge_in (148 dwords ≡ 20 mod 32: 2-way max)
constexpr int EF_STR  = 136; // LDS row stride (bf16) for ef buffers (68 dwords ≡ 4 mod 32: 2-way max)

typedef short s8v __attribute__((ext_vector_type(8)));
typedef float f4v __attribute__((ext_vector_type(4)));

__device__ __forceinline__ ushort f2bf(float f) {
    uint u = __float_as_uint(f);
    uint r = (u + 0x7FFFu + ((u >> 16) & 1u)) >> 16;
    return (ushort)r;
}
__device__ __forceinline__ float bf2f(ushort s) {
    return __uint_as_float(((uint)s) << 16);
}
__device__ __forceinline__ float silu_f(float x) {
    return x * __fdividef(1.0f, 1.0f + __expf(-x));
}

// ---------------- weight pre-swizzle into MFMA B-fragment order ----------------
// dst layout per weight: [kc][t][lane][j] ; element = W[kc*32 + (lane>>4)*8 + j][t*16 + (lane&15)]
__global__ void __launch_bounds__(256) k_swz(
    const float* __restrict__ eW1, const float* __restrict__ eW2, const float* __restrict__ cW1,
    ushort* __restrict__ o1, ushort* __restrict__ o2, ushort* __restrict__ o3)
{
    int gid = blockIdx.x * 256 + threadIdx.x; // total 4*69632 = 278528, exact grid
    int l = gid / 69632, r = gid % 69632;
    const float* src; ushort* dst; int Ks, idx;
    if (r < 36864)      { src = eW1 + (size_t)l * 258 * 128; dst = o1 + l * 36864; Ks = 258; idx = r; }
    else if (r < 53248) { src = eW2 + (size_t)l * 128 * 128; dst = o2 + l * 16384; Ks = 128; idx = r - 36864; }
    else                { src = cW1 + (size_t)l * 128 * 128; dst = o3 + l * 16384; Ks = 128; idx = r - 53248; }
    int fb = idx >> 9, rem = idx & 511;
    int lane = rem >> 3, jj = rem & 7;
    int kc = fb >> 3, t = fb & 7;
    int k = kc * 32 + ((lane >> 4) << 3) + jj;
    int n = t * 16 + (lane & 15);
    float v = (k < Ks) ? src[k * 128 + n] : 0.0f;
    dst[idx] = f2bf(v);
}

// ---------------- incoming-edge histogram (int) ----------------
__global__ void __launch_bounds__(256) k_count(const int* __restrict__ eidx, int* __restrict__ ecnt)
{
    int e = blockIdx.x * 256 + threadIdx.x; // grid exact
    atomicAdd(&ecnt[eidx[Ee + e]], 1);
}

// ---------------- exclusive scan over node counts (single block) ----------------
__global__ void __launch_bounds__(1024) k_scan(const int* __restrict__ ecnt,
                                               int* __restrict__ cursor)
{
    __shared__ int wsum[16];
    __shared__ int carry;
    int tid = threadIdx.x, lane = tid & 63, w = tid >> 6;
    if (tid == 0) carry = 0;
    __syncthreads();
    for (int start = 0; start < Nn; start += 1024) {
        int i = start + tid;
        int x = (i < Nn) ? ecnt[i] : 0;
        int c0 = carry;
        int s = x;
        #pragma unroll
        for (int off = 1; off < 64; off <<= 1) {
            int t = __shfl_up(s, off, 64);
            if (lane >= off) s += t;
        }
        if (lane == 63) wsum[w] = s;
        __syncthreads();
        if (w == 0) {
            int t = (lane < 16) ? wsum[lane] : 0;
            #pragma unroll
            for (int off = 1; off < 16; off <<= 1) {
                int u = __shfl_up(t, off, 64);
                if (lane >= off) t += u;
            }
            if (lane < 16) wsum[lane] = t;
        }
        __syncthreads();
        int woff = (w == 0) ? 0 : wsum[w - 1];
        int excl = c0 + woff + s - x;
        if (i < Nn) cursor[i] = excl;
        int blocksum = wsum[15];
        __syncthreads();
        if (tid == 0) carry = c0 + blocksum;
        __syncthreads();
    }
}

// ---------------- scatter edge ids into col-sorted order ----------------
__global__ void __launch_bounds__(256) k_scatter(const int* __restrict__ eidx,
                                                 int* __restrict__ cursor, int* __restrict__ perm)
{
    int e = blockIdx.x * 256 + threadIdx.x; // grid exact
    int c = eidx[Ee + e];
    int p = atomicAdd(&cursor[c], 1);
    perm[p] = e;
}

// ---------------- input embedding + coord copy ----------------
__global__ void __launch_bounds__(128) k_emb(
    const float* __restrict__ h_in, const float* __restrict__ coords,
    const float* __restrict__ W, const float* __restrict__ b,
    float* __restrict__ hbuf, ushort* __restrict__ hbf, float* __restrict__ cbuf)
{
    __shared__ float sh[64];
    int n = blockIdx.x, j = threadIdx.x;
    if (j < 64) sh[j] = h_in[(size_t)n * 64 + j];
    __syncthreads();
    float acc = b[j];
    #pragma unroll 8
    for (int k = 0; k < 64; k++) acc += sh[k] * W[k * 128 + j];
    hbuf[(size_t)n * 128 + j] = acc;
    hbf[(size_t)n * 128 + j] = f2bf(acc);
    if (j < 3) cbuf[n * 3 + j] = coords[n * 3 + j];
}

// ---------------- fused edge MLP + run-reduced aggregation (MFMA bf16) ----------------
// Edges processed in col-sorted order (perm). Each wave owns 2 of 8 output t-tiles
// for ALL 64 edges (N-split): B-fragment global traffic /4 vs M-split.
__global__ void __launch_bounds__(256, 2) k_edge(
    const ushort* __restrict__ hbf, const float* __restrict__ cbuf,
    const float* __restrict__ edge_attr, const int* __restrict__ eidx,
    const int* __restrict__ perm,
    const ushort* __restrict__ w1s, const float* __restrict__ b1,
    const ushort* __restrict__ w2s, const float* __restrict__ b2,
    const ushort* __restrict__ cw1s, const float* __restrict__ cb1,
    const float* __restrict__ cwc,
    float* __restrict__ agg_feat, float* __restrict__ agg_coord)
{
    __shared__ alignas(16) ushort s_ein[64 * EIN_STR]; // 37.0 KB
    __shared__ alignas(16) ushort s_efa[64 * EF_STR];  // 17.0 KB
    __shared__ alignas(16) ushort s_efb[64 * EF_STR];  // 17.0 KB
    __shared__ int   s_col[64];
    __shared__ int   s_row[64];
    __shared__ float s_cd[64 * 3];
    __shared__ float s_cw[64];

    const int tid = threadIdx.x;
    const int eb = blockIdx.x * 64;

    // --- edge metadata (sorted edge ids via perm) ---
    if (tid < 64) {
        int pe = perm[eb + tid];
        int rw = eidx[pe], cl = eidx[Ee + pe];
        s_row[tid] = rw; s_col[tid] = cl;
        float d0 = cbuf[rw * 3 + 0] - cbuf[cl * 3 + 0];
        float d1 = cbuf[rw * 3 + 1] - cbuf[cl * 3 + 1];
        float d2 = cbuf[rw * 3 + 2] - cbuf[cl * 3 + 2];
        s_cd[tid * 3 + 0] = d0; s_cd[tid * 3 + 1] = d1; s_cd[tid * 3 + 2] = d2;
        float dist = d0 * d0 + d1 * d1 + d2 * d2;
        s_ein[tid * EIN_STR + 256] = f2bf(dist);
        s_ein[tid * EIN_STR + 257] = f2bf(edge_attr[pe]);
        uint* zp = (uint*)(s_ein + tid * EIN_STR + 258); // pad 258..287
        #pragma unroll
        for (int z = 0; z < 15; z++) zp[z] = 0;
        s_cw[tid] = 0.0f;
    }
    __syncthreads();

    // --- gather h[col] (k<128) and h[row] (128..255) as bf16, 16B chunks ---
    #pragma unroll
    for (int i = 0; i < 8; i++) {
        int idx = i * 256 + tid;
        int e = idx >> 5, ch = idx & 31;
        int node = (ch < 16) ? s_col[e] : s_row[e];
        uint4 v = *(const uint4*)(hbf + (size_t)node * 128 + (ch & 15) * 8);
        *(uint4*)(s_ein + e * EIN_STR + ch * 8) = v;
    }
    __syncthreads();

    const int lane = tid & 63, wave = tid >> 6;
    const int m = lane & 15, quad = lane >> 4;

    // ---- GEMM1: [64,288] @ [288,32] per wave (t = 2w, 2w+1) ----
    {
        f4v acc[4][2];
        #pragma unroll
        for (int mt = 0; mt < 4; mt++) { acc[mt][0] = (f4v){0,0,0,0}; acc[mt][1] = (f4v){0,0,0,0}; }
        const ushort* bBase = w1s + (size_t)lane * 8 + (size_t)wave * 1024;
        #pragma unroll
        for (int kc = 0; kc < 9; kc++) {
            s8v b0 = *(const s8v*)(bBase + kc * 4096);
            s8v b1v = *(const s8v*)(bBase + kc * 4096 + 512);
            #pragma unroll
            for (int mt = 0; mt < 4; mt++) {
                s8v a = *(const s8v*)(s_ein + (mt * 16 + m) * EIN_STR + kc * 32 + quad * 8);
                acc[mt][0] = __builtin_amdgcn_mfma_f32_16x16x32_bf16(a, b0, acc[mt][0], 0, 0, 0);
                acc[mt][1] = __builtin_amdgcn_mfma_f32_16x16x32_bf16(a, b1v, acc[mt][1], 0, 0, 0);
            }
        }
        #pragma unroll
        for (int tt = 0; tt < 2; tt++) {
            int col = (wave * 2 + tt) * 16 + m;
            float bias = b1[col];
            #pragma unroll
            for (int mt = 0; mt < 4; mt++)
                #pragma unroll
                for (int r = 0; r < 4; r++)
                    s_efa[(mt * 16 + quad * 4 + r) * EF_STR + col] = f2bf(silu_f(acc[mt][tt][r] + bias));
        }
    }
    __syncthreads();

    // ---- GEMM2: [64,128] @ [128,32] per wave ----
    {
        f4v acc[4][2];
        #pragma unroll
        for (int mt = 0; mt < 4; mt++) { acc[mt][0] = (f4v){0,0,0,0}; acc[mt][1] = (f4v){0,0,0,0}; }
        const ushort* bBase = w2s + (size_t)lane * 8 + (size_t)wave * 1024;
        #pragma unroll
        for (int kc = 0; kc < 4; kc++) {
            s8v b0 = *(const s8v*)(bBase + kc * 4096);
            s8v b1v = *(const s8v*)(bBase + kc * 4096 + 512);
            #pragma unroll
            for (int mt = 0; mt < 4; mt++) {
                s8v a = *(const s8v*)(s_efa + (mt * 16 + m) * EF_STR + kc * 32 + quad * 8);
                acc[mt][0] = __builtin_amdgcn_mfma_f32_16x16x32_bf16(a, b0, acc[mt][0], 0, 0, 0);
                acc[mt][1] = __builtin_amdgcn_mfma_f32_16x16x32_bf16(a, b1v, acc[mt][1], 0, 0, 0);
            }
        }
        #pragma unroll
        for (int tt = 0; tt < 2; tt++) {
            int col = (wave * 2 + tt) * 16 + m;
            float bias = b2[col];
            #pragma unroll
            for (int mt = 0; mt < 4; mt++)
                #pragma unroll
                for (int r = 0; r < 4; r++)
                    s_efb[(mt * 16 + quad * 4 + r) * EF_STR + col] = f2bf(silu_f(acc[mt][tt][r] + bias));
        }
    }
    __syncthreads();

    // ---- coord gate: cw = silu(ef @ cW1 + cb1) @ cWc, partial per wave ----
    {
        f4v acc[4][2];
        #pragma unroll
        for (int mt = 0; mt < 4; mt++) { acc[mt][0] = (f4v){0,0,0,0}; acc[mt][1] = (f4v){0,0,0,0}; }
        const ushort* bBase = cw1s + (size_t)lane * 8 + (size_t)wave * 1024;
        #pragma unroll
        for (int kc = 0; kc < 4; kc++) {
            s8v b0 = *(const s8v*)(bBase + kc * 4096);
            s8v b1v = *(const s8v*)(bBase + kc * 4096 + 512);
            #pragma unroll
            for (int mt = 0; mt < 4; mt++) {
                s8v a = *(const s8v*)(s_efb + (mt * 16 + m) * EF_STR + kc * 32 + quad * 8);
                acc[mt][0] = __builtin_amdgcn_mfma_f32_16x16x32_bf16(a, b0, acc[mt][0], 0, 0, 0);
                acc[mt][1] = __builtin_amdgcn_mfma_f32_16x16x32_bf16(a, b1v, acc[mt][1], 0, 0, 0);
            }
        }
        int c0 = wave * 32 + m, c1 = wave * 32 + 16 + m;
        float bias0 = cb1[c0], wc0 = cwc[c0];
        float bias1 = cb1[c1], wc1 = cwc[c1];
        #pragma unroll
        for (int mt = 0; mt < 4; mt++) {
            float p0 = silu_f(acc[mt][0][0] + bias0) * wc0 + silu_f(acc[mt][1][0] + bias1) * wc1;
            float p1 = silu_f(acc[mt][0][1] + bias0) * wc0 + silu_f(acc[mt][1][1] + bias1) * wc1;
            float p2 = silu_f(acc[mt][0][2] + bias0) * wc0 + silu_f(acc[mt][1][2] + bias1) * wc1;
            float p3 = silu_f(acc[mt][0][3] + bias0) * wc0 + silu_f(acc[mt][1][3] + bias1) * wc1;
            #pragma unroll
            for (int off = 1; off < 16; off <<= 1) {
                p0 += __shfl_xor(p0, off, 64);
                p1 += __shfl_xor(p1, off, 64);
                p2 += __shfl_xor(p2, off, 64);
                p3 += __shfl_xor(p3, off, 64);
            }
            if (m < 4) {
                float v = (m == 0) ? p0 : (m == 1) ? p1 : (m == 2) ? p2 : p3;
                atomicAdd(&s_cw[mt * 16 + quad * 4 + m], v);
            }
        }
    }
    __syncthreads();

    // ---- coord aggregation: run-length scan over sorted cols (12 threads) ----
    if (tid < 12) {
        int d = tid % 3, seg = tid / 3; // 4 segments of 16 edges
        int e0 = seg * 16;
        float acc = 0.0f; int cur = s_col[e0];
        for (int e = e0; e < e0 + 16; e++) {
            int c = s_col[e];
            if (c != cur) {
                unsafeAtomicAdd(&agg_coord[cur * 3 + d], acc);
                acc = 0.0f; cur = c;
            }
            acc += s_cd[e * 3 + d] * s_cw[e];
        }
        unsafeAtomicAdd(&agg_coord[cur * 3 + d], acc);
    }

    // ---- feature aggregation: wave-uniform run-length scan, coalesced atomics ----
    {
        int j = tid & 127;
        int e0 = (tid >> 7) * 32;
        float acc = 0.0f; int cur = s_col[e0];
        #pragma unroll 4
        for (int e = e0; e < e0 + 32; e++) {
            int c = s_col[e]; // uniform across the wave
            if (c != cur) {
                unsafeAtomicAdd(&agg_feat[(size_t)cur * 128 + j], acc);
                acc = 0.0f; cur = c;
            }
            acc += bf2f(s_efb[e * EF_STR + j]);
        }
        unsafeAtomicAdd(&agg_feat[(size_t)cur * 128 + j], acc);
    }
}

// ---------------- node update (fp32 register-tiled) ----------------
__global__ void __launch_bounds__(256, 2) k_node(
    float* __restrict__ hbuf, ushort* __restrict__ hbf, float* __restrict__ cbuf,
    const float* __restrict__ agg_feat, const float* __restrict__ agg_coord,
    const int* __restrict__ ecnt,
    const float* __restrict__ w1, const float* __restrict__ b1,
    const float* __restrict__ w2, const float* __restrict__ b2)
{
    __shared__ alignas(16) float s_a[64 * 36];
    __shared__ alignas(16) float s_t1[64 * 132];
    const int tid = threadIdx.x;
    const int tx = tid & 31, ty = tid >> 5;
    const int nb = blockIdx.x * 64;

    float acc[8][4];
    #pragma unroll
    for (int e = 0; e < 8; e++)
        #pragma unroll
        for (int j = 0; j < 4; j++) acc[e][j] = 0.f;

    // GEMM1: node_in = [h | agg_feat], K=256
    for (int kc = 0; kc < 8; kc++) {
        #pragma unroll
        for (int ii = 0; ii < 2; ii++) {
            int idx4 = ii * 256 + tid;
            int e = idx4 >> 3, seg = idx4 & 7;
            int node = nb + e;
            int k = kc * 32 + seg * 4;
            float4 v = make_float4(0.f, 0.f, 0.f, 0.f);
            if (node < Nn)
                v = (k < 128) ? *(const float4*)(hbuf + (size_t)node * 128 + k)
                              : *(const float4*)(agg_feat + (size_t)node * 128 + (k - 128));
            *(float4*)(s_a + e * 36 + seg * 4) = v;
        }
        __syncthreads();
        #pragma unroll
        for (int kk = 0; kk < 8; kk++) {
            float bb[4][4];
            #pragma unroll
            for (int i = 0; i < 4; i++)
                *(float4*)bb[i] = *(const float4*)(w1 + (size_t)(kc * 32 + kk * 4 + i) * 128 + tx * 4);
            #pragma unroll
            for (int e2 = 0; e2 < 8; e2++) {
                float aa[4];
                *(float4*)aa = *(const float4*)(s_a + (ty * 8 + e2) * 36 + kk * 4);
                #pragma unroll
                for (int i = 0; i < 4; i++)
                    #pragma unroll
                    for (int j = 0; j < 4; j++)
                        acc[e2][j] += aa[i] * bb[i][j];
            }
        }
        __syncthreads();
    }

    // coords += agg_coord / max(counts,1)
    if (tid < 64) {
        int n = nb + tid;
        if (n < Nn) {
            float c = (float)ecnt[n]; c = (c < 1.0f) ? 1.0f : c;
            float inv = __fdividef(1.0f, c);
            cbuf[n * 3 + 0] += agg_coord[n * 3 + 0] * inv;
            cbuf[n * 3 + 1] += agg_coord[n * 3 + 1] * inv;
            cbuf[n * 3 + 2] += agg_coord[n * 3 + 2] * inv;
        }
    }

    // t1 = silu(acc + b1)
    float bb1[4]; *(float4*)bb1 = *(const float4*)(b1 + tx * 4);
    #pragma unroll
    for (int e2 = 0; e2 < 8; e2++) {
        float4 o;
        o.x = silu_f(acc[e2][0] + bb1[0]);
        o.y = silu_f(acc[e2][1] + bb1[1]);
        o.z = silu_f(acc[e2][2] + bb1[2]);
        o.w = silu_f(acc[e2][3] + bb1[3]);
        *(float4*)(s_t1 + (ty * 8 + e2) * 132 + tx * 4) = o;
    }
    __syncthreads();

    // GEMM2: K=128
    float acc2[8][4];
    #pragma unroll
    for (int e = 0; e < 8; e++)
        #pragma unroll
        for (int j = 0; j < 4; j++) acc2[e][j] = 0.f;
    #pragma unroll 4
    for (int kk = 0; kk < 32; kk++) {
        float bb[4][4];
        #pragma unroll
        for (int i = 0; i < 4; i++)
            *(float4*)bb[i] = *(const float4*)(w2 + (size_t)(kk * 4 + i) * 128 + tx * 4);
        #pragma unroll
        for (int e2 = 0; e2 < 8; e2++) {
            float aa[4];
            *(float4*)aa = *(const float4*)(s_t1 + (ty * 8 + e2) * 132 + kk * 4);
            #pragma unroll
            for (int i = 0; i < 4; i++)
                #pragma unroll
                for (int j = 0; j < 4; j++)
                    acc2[e2][j] += aa[i] * bb[i][j];
        }
    }

    // h += upd; refresh bf16 mirror
    float bb2[4]; *(float4*)bb2 = *(const float4*)(b2 + tx * 4);
    #pragma unroll
    for (int e2 = 0; e2 < 8; e2++) {
        int node = nb + ty * 8 + e2;
        if (node < Nn) {
            float4 old = *(const float4*)(hbuf + (size_t)node * 128 + tx * 4);
            float v0 = old.x + acc2[e2][0] + bb2[0];
            float v1 = old.y + acc2[e2][1] + bb2[1];
            float v2 = old.z + acc2[e2][2] + bb2[2];
            float v3 = old.w + acc2[e2][3] + bb2[3];
            float4 nv = make_float4(v0, v1, v2, v3);
            *(float4*)(hbuf + (size_t)node * 128 + tx * 4) = nv;
            ushort4 nb16; nb16.x = f2bf(v0); nb16.y = f2bf(v1); nb16.z = f2bf(v2); nb16.w = f2bf(v3);
            *(ushort4*)(hbf + (size_t)node * 128 + tx * 4) = nb16;
        }
    }
}

// ---------------- output embedding + coords out ----------------
__global__ void __launch_bounds__(256) k_emb_out(
    const float* __restrict__ hbuf, const float* __restrict__ cbuf,
    const float* __restrict__ W, const float* __restrict__ b, float* __restrict__ out)
{
    __shared__ float sh[256];
    int tid = threadIdx.x;
    int local = tid >> 7, j = tid & 127;
    int n = blockIdx.x * 2 + local; // 25000*2 == N exact
    sh[tid] = hbuf[(size_t)n * 128 + j];
    __syncthreads();
    float acc = b[j];
    #pragma unroll 8
    for (int k = 0; k < 128; k++) acc += sh[local * 128 + k] * W[k * 128 + j];
    out[(size_t)n * 128 + j] = acc;
    if (tid < 6) {
        int n2 = blockIdx.x * 2 + tid / 3, d = tid - (tid / 3) * 3;
        out[(size_t)Nn * 128 + n2 * 3 + d] = cbuf[n2 * 3 + d];
    }
}

// ---------------- host launcher ----------------
extern "C" void kernel_launch(void* const* d_in, const int* in_sizes, int n_in,
                              void* d_out, int out_size, void* d_ws, size_t ws_size,
                              hipStream_t stream)
{
    const float* h_in      = (const float*)d_in[0];
    const float* coords    = (const float*)d_in[1];
    const float* edge_attr = (const float*)d_in[2];
    const float* emb_in_W  = (const float*)d_in[3];
    const float* emb_in_b  = (const float*)d_in[4];
    const float* emb_out_W = (const float*)d_in[5];
    const float* emb_out_b = (const float*)d_in[6];
    const float* eW1 = (const float*)d_in[7];
    const float* eb1 = (const float*)d_in[8];
    const float* eW2 = (const float*)d_in[9];
    const float* eb2 = (const float*)d_in[10];
    const float* cW1 = (const float*)d_in[11];
    const float* cb1 = (const float*)d_in[12];
    const float* cWc = (const float*)d_in[13];
    const float* nW1 = (const float*)d_in[14];
    const float* nb1 = (const float*)d_in[15];
    const float* nW2 = (const float*)d_in[16];
    const float* nb2 = (const float*)d_in[17];
    const int*  eidx = (const int*)d_in[18];

    size_t off = 0;
    char* base = (char*)d_ws;
    auto alloc = [&](size_t bytes) -> char* {
        char* p = base + off;
        off += (bytes + 255) & ~(size_t)255;
        return p;
    };
    float*  hbuf      = (float*)alloc((size_t)Nn * 128 * 4);
    ushort* hbf       = (ushort*)alloc((size_t)Nn * 128 * 2);
    float*  cbuf      = (float*)alloc((size_t)Nn * 3 * 4);
    int*    ecnt      = (int*)alloc((size_t)Nn * 4);
    int*    cursor    = (int*)alloc((size_t)Nn * 4);
    int*    perm      = (int*)alloc((size_t)Ee * 4);
    float*  agg_feat  = (float*)alloc((size_t)Nn * 128 * 4);
    float*  agg_coord = (float*)alloc((size_t)Nn * 3 * 4);
    ushort* eW1s      = (ushort*)alloc((size_t)4 * 36864 * 2);
    ushort* eW2s      = (ushort*)alloc((size_t)4 * 16384 * 2);
    ushort* cW1s      = (ushort*)alloc((size_t)4 * 16384 * 2);

    k_swz<<<1088, 256, 0, stream>>>(eW1, eW2, cW1, eW1s, eW2s, cW1s);
    hipMemsetAsync(ecnt, 0, (size_t)Nn * 4, stream);
    k_count<<<Ee / 256, 256, 0, stream>>>(eidx, ecnt);
    k_scan<<<1, 1024, 0, stream>>>(ecnt, cursor);
    k_scatter<<<Ee / 256, 256, 0, stream>>>(eidx, cursor, perm);
    k_emb<<<Nn, 128, 0, stream>>>(h_in, coords, emb_in_W, emb_in_b, hbuf, hbf, cbuf);

    for (int l = 0; l < 4; l++) {
        hipMemsetAsync(agg_feat, 0, (size_t)Nn * 128 * 4, stream);
        hipMemsetAsync(agg_coord, 0, (size_t)Nn * 3 * 4, stream);
        k_edge<<<Ee / 64, 256, 0, stream>>>(
            hbf, cbuf, edge_attr, eidx, perm,
            eW1s + (size_t)l * 36864, eb1 + l * 128,
            eW2s + (size_t)l * 16384, eb2 + l * 128,
            cW1s + (size_t)l * 16384, cb1 + l * 128,
            cWc + l * 128,
            agg_feat, agg_coord);
        k_node<<<(Nn + 63) / 64, 256, 0, stream>>>(
            hbuf, hbf, cbuf, agg_feat, agg_coord, ecnt,
            nW1 + (size_t)l * 256 * 128, nb1 + l * 128,
            nW2 + (size_t)l * 128 * 128, nb2 + l * 128);
    }
    k_emb_out<<<Nn / 2, 256, 0, stream>>>(hbuf, cbuf, emb_out_W, emb_out_b, (float*)d_out);
}

// Round 3
// 1752.686 us; speedup vs baseline: 1.7336x; 1.4466x over previous
//
#include <hip/hip_runtime.h>

// ---------------- problem constants ----------------
constexpr int Nn = 50000;
constexpr int Ee = 800000;
constexpr int EIN_STR = 296; // 148 dw ≡ 20 mod 32 → 2-way max (free)
constexpr int EF_STR  = 136; // 68 dw ≡ 4 mod 32  → 2-way max
constexpr int NIN_STR = 264; // 132 dw ≡ 4 mod 32 → 2-way max
constexpr int HIN_STR = 72;  // 36 dw ≡ 4 mod 32

typedef short s8v __attribute__((ext_vector_type(8)));
typedef float f4v __attribute__((ext_vector_type(4)));

__device__ __forceinline__ ushort f2bf(float f) {
    uint u = __float_as_uint(f);
    uint r = (u + 0x7FFFu + ((u >> 16) & 1u)) >> 16;
    return (ushort)r;
}
__device__ __forceinline__ float bf2f(ushort s) {
    return __uint_as_float(((uint)s) << 16);
}
__device__ __forceinline__ float silu_f(float x) {
    return x * __fdividef(1.0f, 1.0f + __expf(-x));
}

// ---------------- generic weight pre-swizzle into MFMA B-fragment order ----------------
// src: [L, K, 128] ; dst: [L, KC, t(8), lane(64), j(8)]
// element = W[l][kc*32 + (lane>>4)*8 + j][t*16 + (lane&15)], zero-padded past K.
__global__ void __launch_bounds__(256) k_swzg(
    const float* __restrict__ src, ushort* __restrict__ dst, int K, int KC, int total)
{
    int gid = blockIdx.x * 256 + threadIdx.x;
    if (gid >= total) return;
    int per = KC * 4096;
    int l = gid / per, r = gid % per;
    int fb = r >> 9, rem = r & 511;
    int lane = rem >> 3, jj = rem & 7;
    int kc = fb >> 3, t = fb & 7;
    int k = kc * 32 + ((lane >> 4) << 3) + jj;
    int n = t * 16 + (lane & 15);
    float v = (k < K) ? src[(size_t)l * K * 128 + (size_t)k * 128 + n] : 0.0f;
    dst[gid] = f2bf(v);
}

// ---------------- incoming-edge histogram ----------------
__global__ void __launch_bounds__(256) k_count(const int* __restrict__ eidx, int* __restrict__ ecnt)
{
    int e = blockIdx.x * 256 + threadIdx.x;
    atomicAdd(&ecnt[eidx[Ee + e]], 1);
}

// ---------------- exclusive scan over node counts (single block) ----------------
__global__ void __launch_bounds__(1024) k_scan(const int* __restrict__ ecnt, int* __restrict__ cursor)
{
    __shared__ int wsum[16];
    __shared__ int carry;
    int tid = threadIdx.x, lane = tid & 63, w = tid >> 6;
    if (tid == 0) carry = 0;
    __syncthreads();
    for (int start = 0; start < Nn; start += 1024) {
        int i = start + tid;
        int x = (i < Nn) ? ecnt[i] : 0;
        int c0 = carry;
        int s = x;
        #pragma unroll
        for (int off = 1; off < 64; off <<= 1) {
            int t = __shfl_up(s, off, 64);
            if (lane >= off) s += t;
        }
        if (lane == 63) wsum[w] = s;
        __syncthreads();
        if (w == 0) {
            int t = (lane < 16) ? wsum[lane] : 0;
            #pragma unroll
            for (int off = 1; off < 16; off <<= 1) {
                int u = __shfl_up(t, off, 64);
                if (lane >= off) t += u;
            }
            if (lane < 16) wsum[lane] = t;
        }
        __syncthreads();
        int woff = (w == 0) ? 0 : wsum[w - 1];
        if (i < Nn) cursor[i] = c0 + woff + s - x;
        int blocksum = wsum[15];
        __syncthreads();
        if (tid == 0) carry = c0 + blocksum;
        __syncthreads();
    }
}

// ---------------- scatter edges into col-sorted arrays (coalesced consumers) ----------------
__global__ void __launch_bounds__(256) k_scatter(
    const int* __restrict__ eidx, const float* __restrict__ edge_attr,
    int* __restrict__ cursor,
    int* __restrict__ srow, int* __restrict__ scol, float* __restrict__ sattr)
{
    int e = blockIdx.x * 256 + threadIdx.x;
    int r = eidx[e], c = eidx[Ee + e];
    int p = atomicAdd(&cursor[c], 1);
    srow[p] = r; scol[p] = c; sattr[p] = edge_attr[e];
}

// ---------------- input embedding (MFMA bf16, K=64) + coord copy ----------------
__global__ void __launch_bounds__(512, 2) k_emb(
    const float* __restrict__ h_in, const float* __restrict__ coords,
    const ushort* __restrict__ ws_, const float* __restrict__ b,
    float* __restrict__ hbuf, ushort* __restrict__ hbf, float* __restrict__ cbuf)
{
    __shared__ alignas(16) ushort s_h[64 * HIN_STR];
    const int tid = threadIdx.x;
    const int nb = blockIdx.x * 64;
    #pragma unroll
    for (int i = 0; i < 2; i++) {
        int idx = i * 512 + tid;       // 1024 float4 chunks
        int e = idx >> 4, ch = idx & 15;
        int node = nb + e;
        float4 f = make_float4(0.f, 0.f, 0.f, 0.f);
        if (node < Nn) f = *(const float4*)(h_in + (size_t)node * 64 + ch * 4);
        ushort4 u; u.x = f2bf(f.x); u.y = f2bf(f.y); u.z = f2bf(f.z); u.w = f2bf(f.w);
        *(ushort4*)(s_h + e * HIN_STR + ch * 4) = u;
    }
    if (tid < 192) {
        int n = nb + tid / 3, d = tid % 3;
        if (n < Nn) cbuf[n * 3 + d] = coords[n * 3 + d];
    }
    __syncthreads();
    const int lane = tid & 63, wave = tid >> 6;
    const int m = lane & 15, quad = lane >> 4;
    const int ws2 = wave >> 2, wt = wave & 3;
    f4v acc[2][2];
    #pragma unroll
    for (int mt = 0; mt < 2; mt++) { acc[mt][0] = (f4v){0,0,0,0}; acc[mt][1] = (f4v){0,0,0,0}; }
    const ushort* bBase = ws_ + wt * 1024 + lane * 8;
    #pragma unroll
    for (int kc = 0; kc < 2; kc++) {
        s8v b0 = *(const s8v*)(bBase + kc * 4096);
        s8v b1v = *(const s8v*)(bBase + kc * 4096 + 512);
        #pragma unroll
        for (int mt = 0; mt < 2; mt++) {
            s8v a = *(const s8v*)(s_h + (ws2 * 32 + mt * 16 + m) * HIN_STR + kc * 32 + quad * 8);
            acc[mt][0] = __builtin_amdgcn_mfma_f32_16x16x32_bf16(a, b0, acc[mt][0], 0, 0, 0);
            acc[mt][1] = __builtin_amdgcn_mfma_f32_16x16x32_bf16(a, b1v, acc[mt][1], 0, 0, 0);
        }
    }
    #pragma unroll
    for (int tt = 0; tt < 2; tt++) {
        int col = (wt * 2 + tt) * 16 + m;
        float bias = b[col];
        #pragma unroll
        for (int mt = 0; mt < 2; mt++)
            #pragma unroll
            for (int r = 0; r < 4; r++) {
                int node = nb + ws2 * 32 + mt * 16 + quad * 4 + r;
                if (node < Nn) {
                    float v = acc[mt][tt][r] + bias;
                    hbuf[(size_t)node * 128 + col] = v;
                    hbf[(size_t)node * 128 + col] = f2bf(v);
                }
            }
    }
}

// ---------------- fused edge MLP + run-reduced aggregation (MFMA bf16, 8 waves) ----------------
__global__ void __launch_bounds__(512, 2) k_edge(
    const ushort* __restrict__ hbf, const float* __restrict__ cbuf,
    const int* __restrict__ srow, const int* __restrict__ scol, const float* __restrict__ sattr,
    const ushort* __restrict__ w1s, const float* __restrict__ b1,
    const ushort* __restrict__ w2s, const float* __restrict__ b2,
    const ushort* __restrict__ cw1s, const float* __restrict__ cb1,
    const float* __restrict__ cwc,
    float* __restrict__ agg_feat, float* __restrict__ agg_coord)
{
    __shared__ alignas(16) ushort s_ein[64 * EIN_STR]; // 37888 B
    __shared__ alignas(16) ushort s_efa[64 * EF_STR];  // 17408 B
    __shared__ alignas(16) ushort s_efb[64 * EF_STR];  // 17408 B
    __shared__ int   s_col[64];
    __shared__ int   s_row[64];
    __shared__ float s_cd[64 * 3];
    __shared__ float s_cw[64];

    const int tid = threadIdx.x;
    const int eb = blockIdx.x * 64;

    // --- edge metadata (coalesced sorted arrays) ---
    if (tid < 64) {
        int rw = srow[eb + tid], cl = scol[eb + tid];
        s_row[tid] = rw; s_col[tid] = cl;
        float d0 = cbuf[rw * 3 + 0] - cbuf[cl * 3 + 0];
        float d1 = cbuf[rw * 3 + 1] - cbuf[cl * 3 + 1];
        float d2 = cbuf[rw * 3 + 2] - cbuf[cl * 3 + 2];
        s_cd[tid * 3 + 0] = d0; s_cd[tid * 3 + 1] = d1; s_cd[tid * 3 + 2] = d2;
        float dist = d0 * d0 + d1 * d1 + d2 * d2;
        s_ein[tid * EIN_STR + 256] = f2bf(dist);
        s_ein[tid * EIN_STR + 257] = f2bf(sattr[eb + tid]);
        uint* zp = (uint*)(s_ein + tid * EIN_STR + 258);
        #pragma unroll
        for (int z = 0; z < 15; z++) zp[z] = 0;
        s_cw[tid] = 0.0f;
    }
    __syncthreads();

    // --- gather h[col] (k<128) and h[row] (128..255), 16B chunks ---
    #pragma unroll
    for (int i = 0; i < 4; i++) {
        int idx = i * 512 + tid;        // 2048 chunks
        int e = idx >> 5, ch = idx & 31;
        int node = (ch < 16) ? s_col[e] : s_row[e];
        uint4 v = *(const uint4*)(hbf + (size_t)node * 128 + (ch & 15) * 8);
        *(uint4*)(s_ein + e * EIN_STR + ch * 8) = v;
    }
    __syncthreads();

    const int lane = tid & 63, wave = tid >> 6;
    const int m = lane & 15, quad = lane >> 4;
    const int ws2 = wave >> 2, wt = wave & 3;   // ws2: edge half, wt: t-pair
    const int rbase = ws2 * 32;

    // ---- GEMM1: [32,288] @ [288,32] per wave ----
    {
        f4v acc[2][2];
        #pragma unroll
        for (int mt = 0; mt < 2; mt++) { acc[mt][0] = (f4v){0,0,0,0}; acc[mt][1] = (f4v){0,0,0,0}; }
        const ushort* bBase = w1s + wt * 1024 + (size_t)lane * 8;
        #pragma unroll
        for (int kc = 0; kc < 9; kc++) {
            s8v b0 = *(const s8v*)(bBase + kc * 4096);
            s8v b1v = *(const s8v*)(bBase + kc * 4096 + 512);
            #pragma unroll
            for (int mt = 0; mt < 2; mt++) {
                s8v a = *(const s8v*)(s_ein + (rbase + mt * 16 + m) * EIN_STR + kc * 32 + quad * 8);
                acc[mt][0] = __builtin_amdgcn_mfma_f32_16x16x32_bf16(a, b0, acc[mt][0], 0, 0, 0);
                acc[mt][1] = __builtin_amdgcn_mfma_f32_16x16x32_bf16(a, b1v, acc[mt][1], 0, 0, 0);
            }
        }
        #pragma unroll
        for (int tt = 0; tt < 2; tt++) {
            int col = (wt * 2 + tt) * 16 + m;
            float bias = b1[col];
            #pragma unroll
            for (int mt = 0; mt < 2; mt++)
                #pragma unroll
                for (int r = 0; r < 4; r++)
                    s_efa[(rbase + mt * 16 + quad * 4 + r) * EF_STR + col] = f2bf(silu_f(acc[mt][tt][r] + bias));
        }
    }
    __syncthreads();

    // ---- GEMM2: [32,128] @ [128,32] per wave ----
    {
        f4v acc[2][2];
        #pragma unroll
        for (int mt = 0; mt < 2; mt++) { acc[mt][0] = (f4v){0,0,0,0}; acc[mt][1] = (f4v){0,0,0,0}; }
        const ushort* bBase = w2s + wt * 1024 + (size_t)lane * 8;
        #pragma unroll
        for (int kc = 0; kc < 4; kc++) {
            s8v b0 = *(const s8v*)(bBase + kc * 4096);
            s8v b1v = *(const s8v*)(bBase + kc * 4096 + 512);
            #pragma unroll
            for (int mt = 0; mt < 2; mt++) {
                s8v a = *(const s8v*)(s_efa + (rbase + mt * 16 + m) * EF_STR + kc * 32 + quad * 8);
                acc[mt][0] = __builtin_amdgcn_mfma_f32_16x16x32_bf16(a, b0, acc[mt][0], 0, 0, 0);
                acc[mt][1] = __builtin_amdgcn_mfma_f32_16x16x32_bf16(a, b1v, acc[mt][1], 0, 0, 0);
            }
        }
        #pragma unroll
        for (int tt = 0; tt < 2; tt++) {
            int col = (wt * 2 + tt) * 16 + m;
            float bias = b2[col];
            #pragma unroll
            for (int mt = 0; mt < 2; mt++)
                #pragma unroll
                for (int r = 0; r < 4; r++)
                    s_efb[(rbase + mt * 16 + quad * 4 + r) * EF_STR + col] = f2bf(silu_f(acc[mt][tt][r] + bias));
        }
    }
    __syncthreads();

    // ---- coord gate: cw = silu(ef @ cW1 + cb1) @ cWc, partials per wave ----
    {
        f4v acc[2][2];
        #pragma unroll
        for (int mt = 0; mt < 2; mt++) { acc[mt][0] = (f4v){0,0,0,0}; acc[mt][1] = (f4v){0,0,0,0}; }
        const ushort* bBase = cw1s + wt * 1024 + (size_t)lane * 8;
        #pragma unroll
        for (int kc = 0; kc < 4; kc++) {
            s8v b0 = *(const s8v*)(bBase + kc * 4096);
            s8v b1v = *(const s8v*)(bBase + kc * 4096 + 512);
            #pragma unroll
            for (int mt = 0; mt < 2; mt++) {
                s8v a = *(const s8v*)(s_efb + (rbase + mt * 16 + m) * EF_STR + kc * 32 + quad * 8);
                acc[mt][0] = __builtin_amdgcn_mfma_f32_16x16x32_bf16(a, b0, acc[mt][0], 0, 0, 0);
                acc[mt][1] = __builtin_amdgcn_mfma_f32_16x16x32_bf16(a, b1v, acc[mt][1], 0, 0, 0);
            }
        }
        int c0 = wt * 32 + m, c1 = wt * 32 + 16 + m;
        float bias0 = cb1[c0], wc0 = cwc[c0];
        float bias1 = cb1[c1], wc1 = cwc[c1];
        #pragma unroll
        for (int mt = 0; mt < 2; mt++) {
            float p0 = silu_f(acc[mt][0][0] + bias0) * wc0 + silu_f(acc[mt][1][0] + bias1) * wc1;
            float p1 = silu_f(acc[mt][0][1] + bias0) * wc0 + silu_f(acc[mt][1][1] + bias1) * wc1;
            float p2 = silu_f(acc[mt][0][2] + bias0) * wc0 + silu_f(acc[mt][1][2] + bias1) * wc1;
            float p3 = silu_f(acc[mt][0][3] + bias0) * wc0 + silu_f(acc[mt][1][3] + bias1) * wc1;
            #pragma unroll
            for (int off = 1; off < 16; off <<= 1) {
                p0 += __shfl_xor(p0, off, 64);
                p1 += __shfl_xor(p1, off, 64);
                p2 += __shfl_xor(p2, off, 64);
                p3 += __shfl_xor(p3, off, 64);
            }
            if (m < 4) {
                float v = (m == 0) ? p0 : (m == 1) ? p1 : (m == 2) ? p2 : p3;
                atomicAdd(&s_cw[rbase + mt * 16 + quad * 4 + m], v);
            }
        }
    }
    __syncthreads();

    // ---- coord aggregation: run-length scan over sorted cols ----
    if (tid < 12) {
        int d = tid % 3, seg = tid / 3;
        int e0 = seg * 16;
        float acc = 0.0f; int cur = s_col[e0];
        for (int e = e0; e < e0 + 16; e++) {
            int c = s_col[e];
            if (c != cur) {
                unsafeAtomicAdd(&agg_coord[cur * 3 + d], acc);
                acc = 0.0f; cur = c;
            }
            acc += s_cd[e * 3 + d] * s_cw[e];
        }
        unsafeAtomicAdd(&agg_coord[cur * 3 + d], acc);
    }

    // ---- feature aggregation: wave-uniform run-length scan, coalesced atomics ----
    {
        int j = tid & 127;
        int e0 = (tid >> 7) * 16;
        float acc = 0.0f; int cur = s_col[e0];
        #pragma unroll 4
        for (int e = e0; e < e0 + 16; e++) {
            int c = s_col[e]; // uniform across the wave
            if (c != cur) {
                unsafeAtomicAdd(&agg_feat[(size_t)cur * 128 + j], acc);
                acc = 0.0f; cur = c;
            }
            acc += bf2f(s_efb[e * EF_STR + j]);
        }
        unsafeAtomicAdd(&agg_feat[(size_t)cur * 128 + j], acc);
    }
}

// ---------------- node update (MFMA bf16) ----------------
__global__ void __launch_bounds__(512, 2) k_node(
    float* __restrict__ hbuf, ushort* __restrict__ hbf, float* __restrict__ cbuf,
    const float* __restrict__ agg_feat, const float* __restrict__ agg_coord,
    const int* __restrict__ ecnt,
    const ushort* __restrict__ w1s, const float* __restrict__ b1,
    const ushort* __restrict__ w2s, const float* __restrict__ b2)
{
    __shared__ alignas(16) ushort s_nin[64 * NIN_STR]; // 33792 B
    __shared__ alignas(16) ushort s_t1[64 * EF_STR];   // 17408 B
    const int tid = threadIdx.x;
    const int nb = blockIdx.x * 64;

    // h (bf16 mirror) → K 0..127
    #pragma unroll
    for (int i = 0; i < 2; i++) {
        int idx = i * 512 + tid;
        int e = idx >> 4, ch = idx & 15;
        int node = nb + e;
        uint4 v = make_uint4(0, 0, 0, 0);
        if (node < Nn) v = *(const uint4*)(hbf + (size_t)node * 128 + ch * 8);
        *(uint4*)(s_nin + e * NIN_STR + ch * 8) = v;
    }
    // agg_feat fp32 → bf16 → K 128..255
    #pragma unroll
    for (int i = 0; i < 4; i++) {
        int idx = i * 512 + tid;
        int e = idx >> 5, ch = idx & 31;
        int node = nb + e;
        float4 f = make_float4(0.f, 0.f, 0.f, 0.f);
        if (node < Nn) f = *(const float4*)(agg_feat + (size_t)node * 128 + ch * 4);
        ushort4 u; u.x = f2bf(f.x); u.y = f2bf(f.y); u.z = f2bf(f.z); u.w = f2bf(f.w);
        *(ushort4*)(s_nin + e * NIN_STR + 128 + ch * 4) = u;
    }
    // coords += agg_coord / max(counts,1)
    if (tid < 64) {
        int n = nb + tid;
        if (n < Nn) {
            float c = (float)ecnt[n]; c = (c < 1.0f) ? 1.0f : c;
            float inv = __fdividef(1.0f, c);
            cbuf[n * 3 + 0] += agg_coord[n * 3 + 0] * inv;
            cbuf[n * 3 + 1] += agg_coord[n * 3 + 1] * inv;
            cbuf[n * 3 + 2] += agg_coord[n * 3 + 2] * inv;
        }
    }
    __syncthreads();

    const int lane = tid & 63, wave = tid >> 6;
    const int m = lane & 15, quad = lane >> 4;
    const int ws2 = wave >> 2, wt = wave & 3;
    const int rbase = ws2 * 32;

    // GEMM1: K=256
    {
        f4v acc[2][2];
        #pragma unroll
        for (int mt = 0; mt < 2; mt++) { acc[mt][0] = (f4v){0,0,0,0}; acc[mt][1] = (f4v){0,0,0,0}; }
        const ushort* bBase = w1s + wt * 1024 + (size_t)lane * 8;
        #pragma unroll
        for (int kc = 0; kc < 8; kc++) {
            s8v b0 = *(const s8v*)(bBase + kc * 4096);
            s8v b1v = *(const s8v*)(bBase + kc * 4096 + 512);
            #pragma unroll
            for (int mt = 0; mt < 2; mt++) {
                s8v a = *(const s8v*)(s_nin + (rbase + mt * 16 + m) * NIN_STR + kc * 32 + quad * 8);
                acc[mt][0] = __builtin_amdgcn_mfma_f32_16x16x32_bf16(a, b0, acc[mt][0], 0, 0, 0);
                acc[mt][1] = __builtin_amdgcn_mfma_f32_16x16x32_bf16(a, b1v, acc[mt][1], 0, 0, 0);
            }
        }
        #pragma unroll
        for (int tt = 0; tt < 2; tt++) {
            int col = (wt * 2 + tt) * 16 + m;
            float bias = b1[col];
            #pragma unroll
            for (int mt = 0; mt < 2; mt++)
                #pragma unroll
                for (int r = 0; r < 4; r++)
                    s_t1[(rbase + mt * 16 + quad * 4 + r) * EF_STR + col] = f2bf(silu_f(acc[mt][tt][r] + bias));
        }
    }
    __syncthreads();

    // GEMM2: K=128, residual epilogue
    {
        f4v acc[2][2];
        #pragma unroll
        for (int mt = 0; mt < 2; mt++) { acc[mt][0] = (f4v){0,0,0,0}; acc[mt][1] = (f4v){0,0,0,0}; }
        const ushort* bBase = w2s + wt * 1024 + (size_t)lane * 8;
        #pragma unroll
        for (int kc = 0; kc < 4; kc++) {
            s8v b0 = *(const s8v*)(bBase + kc * 4096);
            s8v b1v = *(const s8v*)(bBase + kc * 4096 + 512);
            #pragma unroll
            for (int mt = 0; mt < 2; mt++) {
                s8v a = *(const s8v*)(s_t1 + (rbase + mt * 16 + m) * EF_STR + kc * 32 + quad * 8);
                acc[mt][0] = __builtin_amdgcn_mfma_f32_16x16x32_bf16(a, b0, acc[mt][0], 0, 0, 0);
                acc[mt][1] = __builtin_amdgcn_mfma_f32_16x16x32_bf16(a, b1v, acc[mt][1], 0, 0, 0);
            }
        }
        #pragma unroll
        for (int tt = 0; tt < 2; tt++) {
            int col = (wt * 2 + tt) * 16 + m;
            float bias = b2[col];
            #pragma unroll
            for (int mt = 0; mt < 2; mt++)
                #pragma unroll
                for (int r = 0; r < 4; r++) {
                    int node = nb + rbase + mt * 16 + quad * 4 + r;
                    if (node < Nn) {
                        float v = hbuf[(size_t)node * 128 + col] + acc[mt][tt][r] + bias;
                        hbuf[(size_t)node * 128 + col] = v;
                        hbf[(size_t)node * 128 + col] = f2bf(v);
                    }
                }
        }
    }
}

// ---------------- output embedding (MFMA bf16) + coords out ----------------
__global__ void __launch_bounds__(512, 2) k_emb_out(
    const ushort* __restrict__ hbf, const float* __restrict__ cbuf,
    const ushort* __restrict__ ws_, const float* __restrict__ b, float* __restrict__ out)
{
    __shared__ alignas(16) ushort s_h[64 * EF_STR];
    const int tid = threadIdx.x;
    const int nb = blockIdx.x * 64;
    #pragma unroll
    for (int i = 0; i < 2; i++) {
        int idx = i * 512 + tid;
        int e = idx >> 4, ch = idx & 15;
        int node = nb + e;
        uint4 v = make_uint4(0, 0, 0, 0);
        if (node < Nn) v = *(const uint4*)(hbf + (size_t)node * 128 + ch * 8);
        *(uint4*)(s_h + e * EF_STR + ch * 8) = v;
    }
    if (tid < 192) {
        int n = nb + tid / 3, d = tid % 3;
        if (n < Nn) out[(size_t)Nn * 128 + n * 3 + d] = cbuf[n * 3 + d];
    }
    __syncthreads();
    const int lane = tid & 63, wave = tid >> 6;
    const int m = lane & 15, quad = lane >> 4;
    const int ws2 = wave >> 2, wt = wave & 3;
    f4v acc[2][2];
    #pragma unroll
    for (int mt = 0; mt < 2; mt++) { acc[mt][0] = (f4v){0,0,0,0}; acc[mt][1] = (f4v){0,0,0,0}; }
    const ushort* bBase = ws_ + wt * 1024 + (size_t)lane * 8;
    #pragma unroll
    for (int kc = 0; kc < 4; kc++) {
        s8v b0 = *(const s8v*)(bBase + kc * 4096);
        s8v b1v = *(const s8v*)(bBase + kc * 4096 + 512);
        #pragma unroll
        for (int mt = 0; mt < 2; mt++) {
            s8v a = *(const s8v*)(s_h + (ws2 * 32 + mt * 16 + m) * EF_STR + kc * 32 + quad * 8);
            acc[mt][0] = __builtin_amdgcn_mfma_f32_16x16x32_bf16(a, b0, acc[mt][0], 0, 0, 0);
            acc[mt][1] = __builtin_amdgcn_mfma_f32_16x16x32_bf16(a, b1v, acc[mt][1], 0, 0, 0);
        }
    }
    #pragma unroll
    for (int tt = 0; tt < 2; tt++) {
        int col = (wt * 2 + tt) * 16 + m;
        float bias = b[col];
        #pragma unroll
        for (int mt = 0; mt < 2; mt++)
            #pragma unroll
            for (int r = 0; r < 4; r++) {
                int node = nb + ws2 * 32 + mt * 16 + quad * 4 + r;
                if (node < Nn) out[(size_t)node * 128 + col] = acc[mt][tt][r] + bias;
            }
    }
}

// ---------------- host launcher ----------------
extern "C" void kernel_launch(void* const* d_in, const int* in_sizes, int n_in,
                              void* d_out, int out_size, void* d_ws, size_t ws_size,
                              hipStream_t stream)
{
    const float* h_in      = (const float*)d_in[0];
    const float* coords    = (const float*)d_in[1];
    const float* edge_attr = (const float*)d_in[2];
    const float* emb_in_W  = (const float*)d_in[3];
    const float* emb_in_b  = (const float*)d_in[4];
    const float* emb_out_W = (const float*)d_in[5];
    const float* emb_out_b = (const float*)d_in[6];
    const float* eW1 = (const float*)d_in[7];
    const float* eb1 = (const float*)d_in[8];
    const float* eW2 = (const float*)d_in[9];
    const float* eb2 = (const float*)d_in[10];
    const float* cW1 = (const float*)d_in[11];
    const float* cb1 = (const float*)d_in[12];
    const float* cWc = (const float*)d_in[13];
    const float* nW1 = (const float*)d_in[14];
    const float* nb1 = (const float*)d_in[15];
    const float* nW2 = (const float*)d_in[16];
    const float* nb2 = (const float*)d_in[17];
    const int*  eidx = (const int*)d_in[18];

    size_t off = 0;
    char* base = (char*)d_ws;
    auto alloc = [&](size_t bytes) -> char* {
        char* p = base + off;
        off += (bytes + 255) & ~(size_t)255;
        return p;
    };
    float*  hbuf      = (float*)alloc((size_t)Nn * 128 * 4);
    ushort* hbf       = (ushort*)alloc((size_t)Nn * 128 * 2);
    float*  cbuf      = (float*)alloc((size_t)Nn * 3 * 4);
    int*    ecnt      = (int*)alloc((size_t)Nn * 4);
    int*    cursor    = (int*)alloc((size_t)Nn * 4);
    int*    srow      = (int*)alloc((size_t)Ee * 4);
    int*    scol      = (int*)alloc((size_t)Ee * 4);
    float*  sattr     = (float*)alloc((size_t)Ee * 4);
    float*  agg_feat  = (float*)alloc((size_t)Nn * 128 * 4);
    float*  agg_coord = (float*)alloc((size_t)Nn * 3 * 4);
    ushort* eW1s      = (ushort*)alloc((size_t)4 * 36864 * 2);
    ushort* eW2s      = (ushort*)alloc((size_t)4 * 16384 * 2);
    ushort* cW1s      = (ushort*)alloc((size_t)4 * 16384 * 2);
    ushort* nW1s      = (ushort*)alloc((size_t)4 * 32768 * 2);
    ushort* nW2s      = (ushort*)alloc((size_t)4 * 16384 * 2);
    ushort* eInWs     = (ushort*)alloc((size_t)8192 * 2);
    ushort* eOutWs    = (ushort*)alloc((size_t)16384 * 2);

    // weight swizzles (tiny)
    k_swzg<<<(4*9*4096+255)/256, 256, 0, stream>>>(eW1, eW1s, 258, 9, 4*9*4096);
    k_swzg<<<(4*4*4096+255)/256, 256, 0, stream>>>(eW2, eW2s, 128, 4, 4*4*4096);
    k_swzg<<<(4*4*4096+255)/256, 256, 0, stream>>>(cW1, cW1s, 128, 4, 4*4*4096);
    k_swzg<<<(4*8*4096+255)/256, 256, 0, stream>>>(nW1, nW1s, 256, 8, 4*8*4096);
    k_swzg<<<(4*4*4096+255)/256, 256, 0, stream>>>(nW2, nW2s, 128, 4, 4*4*4096);
    k_swzg<<<(2*4096+255)/256,   256, 0, stream>>>(emb_in_W,  eInWs,  64, 2, 2*4096);
    k_swzg<<<(4*4096+255)/256,   256, 0, stream>>>(emb_out_W, eOutWs, 128, 4, 4*4096);

    hipMemsetAsync(ecnt, 0, (size_t)Nn * 4, stream);
    k_count<<<Ee / 256, 256, 0, stream>>>(eidx, ecnt);
    k_scan<<<1, 1024, 0, stream>>>(ecnt, cursor);
    k_scatter<<<Ee / 256, 256, 0, stream>>>(eidx, edge_attr, cursor, srow, scol, sattr);
    k_emb<<<(Nn + 63) / 64, 512, 0, stream>>>(h_in, coords, eInWs, emb_in_b, hbuf, hbf, cbuf);

    for (int l = 0; l < 4; l++) {
        hipMemsetAsync(agg_feat, 0, (size_t)Nn * 128 * 4, stream);
        hipMemsetAsync(agg_coord, 0, (size_t)Nn * 3 * 4, stream);
        k_edge<<<Ee / 64, 512, 0, stream>>>(
            hbf, cbuf, srow, scol, sattr,
            eW1s + (size_t)l * 36864, eb1 + l * 128,
            eW2s + (size_t)l * 16384, eb2 + l * 128,
            cW1s + (size_t)l * 16384, cb1 + l * 128,
            cWc + l * 128,
            agg_feat, agg_coord);
        k_node<<<(Nn + 63) / 64, 512, 0, stream>>>(
            hbuf, hbf, cbuf, agg_feat, agg_coord, ecnt,
            nW1s + (size_t)l * 32768, nb1 + l * 128,
            nW2s + (size_t)l * 16384, nb2 + l * 128);
    }
    k_emb_out<<<(Nn + 63) / 64, 512, 0, stream>>>(hbf, cbuf, eOutWs, emb_out_b, (float*)d_out);
}

// Round 4
// 1712.533 us; speedup vs baseline: 1.7742x; 1.0234x over previous
//
#include <hip/hip_runtime.h>

// ---------------- problem constants ----------------
constexpr int Nn = 50000;
constexpr int Ee = 800000;
constexpr int EF_STR  = 136; // 68 dw ≡ 4 mod 32 → 2-way (free), 16B-aligned rows
constexpr int TL_STR  = 40;  // tail stride: 20 dw ≡ 20 mod 32 → 2-way (free)
constexpr int NIN_STR = 264; // 132 dw ≡ 4 mod 32 → 2-way
constexpr int HIN_STR = 72;  // 36 dw ≡ 4 mod 32

typedef short s8v __attribute__((ext_vector_type(8)));
typedef float f4v __attribute__((ext_vector_type(4)));

__device__ __forceinline__ ushort f2bf(float f) {      // RNE (cold paths)
    uint u = __float_as_uint(f);
    uint r = (u + 0x7FFFu + ((u >> 16) & 1u)) >> 16;
    return (ushort)r;
}
__device__ __forceinline__ ushort f2bf_t(float f) {    // truncate (hot paths; d16_hi pattern)
    return (ushort)(__float_as_uint(f) >> 16);
}
__device__ __forceinline__ float bf2f(ushort s) {
    return __uint_as_float(((uint)s) << 16);
}
__device__ __forceinline__ float silu_f(float x) {
    return x * __fdividef(1.0f, 1.0f + __expf(-x));
}

// ---------------- generic weight pre-swizzle into MFMA B-fragment order ----------------
// src: [L, K, 128] ; dst: [L, KC, t(8), lane(64), j(8)]
// element = W[l][kc*32 + (lane>>4)*8 + j][t*16 + (lane&15)], zero-padded past K.
__global__ void __launch_bounds__(256) k_swzg(
    const float* __restrict__ src, ushort* __restrict__ dst, int K, int KC, int total)
{
    int gid = blockIdx.x * 256 + threadIdx.x;
    if (gid >= total) return;
    int per = KC * 4096;
    int l = gid / per, r = gid % per;
    int fb = r >> 9, rem = r & 511;
    int lane = rem >> 3, jj = rem & 7;
    int kc = fb >> 3, t = fb & 7;
    int k = kc * 32 + ((lane >> 4) << 3) + jj;
    int n = t * 16 + (lane & 15);
    float v = (k < K) ? src[(size_t)l * K * 128 + (size_t)k * 128 + n] : 0.0f;
    dst[gid] = f2bf(v);
}

// ---------------- incoming-edge histogram ----------------
__global__ void __launch_bounds__(256) k_count(const int* __restrict__ eidx, int* __restrict__ ecnt)
{
    int e = blockIdx.x * 256 + threadIdx.x;
    atomicAdd(&ecnt[eidx[Ee + e]], 1);
}

// ---------------- exclusive scan over node counts (single block) ----------------
__global__ void __launch_bounds__(1024) k_scan(const int* __restrict__ ecnt, int* __restrict__ cursor)
{
    __shared__ int wsum[16];
    __shared__ int carry;
    int tid = threadIdx.x, lane = tid & 63, w = tid >> 6;
    if (tid == 0) carry = 0;
    __syncthreads();
    for (int start = 0; start < Nn; start += 1024) {
        int i = start + tid;
        int x = (i < Nn) ? ecnt[i] : 0;
        int c0 = carry;
        int s = x;
        #pragma unroll
        for (int off = 1; off < 64; off <<= 1) {
            int t = __shfl_up(s, off, 64);
            if (lane >= off) s += t;
        }
        if (lane == 63) wsum[w] = s;
        __syncthreads();
        if (w == 0) {
            int t = (lane < 16) ? wsum[lane] : 0;
            #pragma unroll
            for (int off = 1; off < 16; off <<= 1) {
                int u = __shfl_up(t, off, 64);
                if (lane >= off) t += u;
            }
            if (lane < 16) wsum[lane] = t;
        }
        __syncthreads();
        int woff = (w == 0) ? 0 : wsum[w - 1];
        if (i < Nn) cursor[i] = c0 + woff + s - x;
        int blocksum = wsum[15];
        __syncthreads();
        if (tid == 0) carry = c0 + blocksum;
        __syncthreads();
    }
}

// ---------------- scatter edges into col-sorted arrays ----------------
__global__ void __launch_bounds__(256) k_scatter(
    const int* __restrict__ eidx, const float* __restrict__ edge_attr,
    int* __restrict__ cursor,
    int* __restrict__ srow, int* __restrict__ scol, float* __restrict__ sattr)
{
    int e = blockIdx.x * 256 + threadIdx.x;
    int r = eidx[e], c = eidx[Ee + e];
    int p = atomicAdd(&cursor[c], 1);
    srow[p] = r; scol[p] = c; sattr[p] = edge_attr[e];
}

// ---------------- input embedding (MFMA bf16, K=64) + coord copy ----------------
__global__ void __launch_bounds__(512, 2) k_emb(
    const float* __restrict__ h_in, const float* __restrict__ coords,
    const ushort* __restrict__ ws_, const float* __restrict__ b,
    float* __restrict__ hbuf, ushort* __restrict__ hbf, float* __restrict__ cbuf)
{
    __shared__ alignas(16) ushort s_h[64 * HIN_STR];
    const int tid = threadIdx.x;
    const int nb = blockIdx.x * 64;
    #pragma unroll
    for (int i = 0; i < 2; i++) {
        int idx = i * 512 + tid;
        int e = idx >> 4, ch = idx & 15;
        int node = nb + e;
        float4 f = make_float4(0.f, 0.f, 0.f, 0.f);
        if (node < Nn) f = *(const float4*)(h_in + (size_t)node * 64 + ch * 4);
        ushort4 u; u.x = f2bf(f.x); u.y = f2bf(f.y); u.z = f2bf(f.z); u.w = f2bf(f.w);
        *(ushort4*)(s_h + e * HIN_STR + ch * 4) = u;
    }
    if (tid < 192) {
        int n = nb + tid / 3, d = tid % 3;
        if (n < Nn) cbuf[n * 3 + d] = coords[n * 3 + d];
    }
    __syncthreads();
    const int lane = tid & 63, wave = tid >> 6;
    const int m = lane & 15, quad = lane >> 4;
    const int ws2 = wave >> 2, wt = wave & 3;
    f4v acc[2][2];
    #pragma unroll
    for (int mt = 0; mt < 2; mt++) { acc[mt][0] = (f4v){0,0,0,0}; acc[mt][1] = (f4v){0,0,0,0}; }
    const ushort* bBase = ws_ + wt * 1024 + lane * 8;
    #pragma unroll
    for (int kc = 0; kc < 2; kc++) {
        s8v b0 = *(const s8v*)(bBase + kc * 4096);
        s8v b1v = *(const s8v*)(bBase + kc * 4096 + 512);
        #pragma unroll
        for (int mt = 0; mt < 2; mt++) {
            s8v a = *(const s8v*)(s_h + (ws2 * 32 + mt * 16 + m) * HIN_STR + kc * 32 + quad * 8);
            acc[mt][0] = __builtin_amdgcn_mfma_f32_16x16x32_bf16(a, b0, acc[mt][0], 0, 0, 0);
            acc[mt][1] = __builtin_amdgcn_mfma_f32_16x16x32_bf16(a, b1v, acc[mt][1], 0, 0, 0);
        }
    }
    #pragma unroll
    for (int tt = 0; tt < 2; tt++) {
        int col = (wt * 2 + tt) * 16 + m;
        float bias = b[col];
        #pragma unroll
        for (int mt = 0; mt < 2; mt++)
            #pragma unroll
            for (int r = 0; r < 4; r++) {
                int node = nb + ws2 * 32 + mt * 16 + quad * 4 + r;
                if (node < Nn) {
                    float v = acc[mt][tt][r] + bias;
                    hbuf[(size_t)node * 128 + col] = v;
                    hbf[(size_t)node * 128 + col] = f2bf(v);
                }
            }
    }
}

// ---------------- fused edge MLP + run-reduced aggregation ----------------
// LDS plan (41.5 KB → 3 blocks/CU):
//   s_a : h[col] (K 0..127)   → reused for efa (GEMM1 output)
//   s_b : h[row] (K 128..255) → reused for efb (GEMM2 output)
//   s_t : K tail (dist,attr,pad) → reused for coord-gate partial sums (f32, stride 20)
__global__ void __launch_bounds__(512, 6) k_edge(
    const ushort* __restrict__ hbf, const float* __restrict__ cbuf,
    const int* __restrict__ srow, const int* __restrict__ scol, const float* __restrict__ sattr,
    const ushort* __restrict__ w1s, const float* __restrict__ b1,
    const ushort* __restrict__ w2s, const float* __restrict__ b2,
    const ushort* __restrict__ cw1s, const float* __restrict__ cb1,
    const float* __restrict__ cwc,
    float* __restrict__ agg_feat, float* __restrict__ agg_coord)
{
    __shared__ alignas(16) ushort s_a[64 * EF_STR];  // 17408 B
    __shared__ alignas(16) ushort s_b[64 * EF_STR];  // 17408 B
    __shared__ alignas(16) ushort s_t[64 * TL_STR];  // 5120 B (= 64*20 floats when reused)
    __shared__ int   s_col[64];
    __shared__ float s_cd[64 * 3];

    const int tid = threadIdx.x;
    const int eb = blockIdx.x * 64;

    // --- edge metadata (coalesced sorted arrays; no barrier needed before gather) ---
    if (tid < 64) {
        int rw = srow[eb + tid], cl = scol[eb + tid];
        s_col[tid] = cl;
        float d0 = cbuf[rw * 3 + 0] - cbuf[cl * 3 + 0];
        float d1 = cbuf[rw * 3 + 1] - cbuf[cl * 3 + 1];
        float d2 = cbuf[rw * 3 + 2] - cbuf[cl * 3 + 2];
        s_cd[tid * 3 + 0] = d0; s_cd[tid * 3 + 1] = d1; s_cd[tid * 3 + 2] = d2;
        float dist = d0 * d0 + d1 * d1 + d2 * d2;
        s_t[tid * TL_STR + 0] = f2bf(dist);
        s_t[tid * TL_STR + 1] = f2bf(sattr[eb + tid]);
        uint* zp = (uint*)(s_t + tid * TL_STR + 2); // zero k 258..287 (15 dwords)
        #pragma unroll
        for (int z = 0; z < 15; z++) zp[z] = 0;
    }
    // --- gather h[col]→s_a, h[row]→s_b (node ids direct from global: wave-broadcast reads) ---
    #pragma unroll
    for (int i = 0; i < 4; i++) {
        int idx = i * 512 + tid;          // 2048 16B chunks
        int e = idx >> 5, ch = idx & 31;
        int node = (ch < 16) ? scol[eb + e] : srow[eb + e];
        uint4 v = *(const uint4*)(hbf + (size_t)node * 128 + (ch & 15) * 8);
        ushort* dst = (ch < 16) ? (s_a + e * EF_STR + ch * 8)
                                : (s_b + e * EF_STR + (ch - 16) * 8);
        *(uint4*)dst = v;
    }
    __syncthreads(); // B1: staging complete

    const int lane = tid & 63, wave = tid >> 6;
    const int m = lane & 15, quad = lane >> 4;
    const int ws2 = wave >> 2, wt = wave & 3;
    const int rbase = ws2 * 32;

    // ---- GEMM1: [32,288] @ [288,32] per wave ----
    f4v acc[2][2];
    #pragma unroll
    for (int mt = 0; mt < 2; mt++) { acc[mt][0] = (f4v){0,0,0,0}; acc[mt][1] = (f4v){0,0,0,0}; }
    {
        const ushort* bBase = w1s + wt * 1024 + (size_t)lane * 8;
        #pragma unroll
        for (int kc = 0; kc < 4; kc++) {      // K 0..127 from s_a (h[col])
            s8v b0 = *(const s8v*)(bBase + kc * 4096);
            s8v b1v = *(const s8v*)(bBase + kc * 4096 + 512);
            #pragma unroll
            for (int mt = 0; mt < 2; mt++) {
                s8v a = *(const s8v*)(s_a + (rbase + mt * 16 + m) * EF_STR + kc * 32 + quad * 8);
                acc[mt][0] = __builtin_amdgcn_mfma_f32_16x16x32_bf16(a, b0, acc[mt][0], 0, 0, 0);
                acc[mt][1] = __builtin_amdgcn_mfma_f32_16x16x32_bf16(a, b1v, acc[mt][1], 0, 0, 0);
            }
        }
        #pragma unroll
        for (int kc = 4; kc < 8; kc++) {      // K 128..255 from s_b (h[row])
            s8v b0 = *(const s8v*)(bBase + kc * 4096);
            s8v b1v = *(const s8v*)(bBase + kc * 4096 + 512);
            #pragma unroll
            for (int mt = 0; mt < 2; mt++) {
                s8v a = *(const s8v*)(s_b + (rbase + mt * 16 + m) * EF_STR + (kc - 4) * 32 + quad * 8);
                acc[mt][0] = __builtin_amdgcn_mfma_f32_16x16x32_bf16(a, b0, acc[mt][0], 0, 0, 0);
                acc[mt][1] = __builtin_amdgcn_mfma_f32_16x16x32_bf16(a, b1v, acc[mt][1], 0, 0, 0);
            }
        }
        {                                      // K 256..287 from s_t
            s8v b0 = *(const s8v*)(bBase + 8 * 4096);
            s8v b1v = *(const s8v*)(bBase + 8 * 4096 + 512);
            #pragma unroll
            for (int mt = 0; mt < 2; mt++) {
                s8v a = *(const s8v*)(s_t + (rbase + mt * 16 + m) * TL_STR + quad * 8);
                acc[mt][0] = __builtin_amdgcn_mfma_f32_16x16x32_bf16(a, b0, acc[mt][0], 0, 0, 0);
                acc[mt][1] = __builtin_amdgcn_mfma_f32_16x16x32_bf16(a, b1v, acc[mt][1], 0, 0, 0);
            }
        }
    }
    __syncthreads(); // B2: all GEMM1 reads done — s_a/s_b/s_t reusable

    // epilogue1 → s_a (truncating bf16 stores: ds_write_b16_d16_hi)
    #pragma unroll
    for (int tt = 0; tt < 2; tt++) {
        int col = (wt * 2 + tt) * 16 + m;
        float bias = b1[col];
        #pragma unroll
        for (int mt = 0; mt < 2; mt++)
            #pragma unroll
            for (int r = 0; r < 4; r++)
                s_a[(rbase + mt * 16 + quad * 4 + r) * EF_STR + col] = f2bf_t(silu_f(acc[mt][tt][r] + bias));
    }
    __syncthreads(); // B3: efa ready

    // ---- GEMM2: [32,128] @ [128,32] per wave; epilogue → s_b ----
    {
        f4v acc2[2][2];
        #pragma unroll
        for (int mt = 0; mt < 2; mt++) { acc2[mt][0] = (f4v){0,0,0,0}; acc2[mt][1] = (f4v){0,0,0,0}; }
        const ushort* bBase = w2s + wt * 1024 + (size_t)lane * 8;
        #pragma unroll
        for (int kc = 0; kc < 4; kc++) {
            s8v b0 = *(const s8v*)(bBase + kc * 4096);
            s8v b1v = *(const s8v*)(bBase + kc * 4096 + 512);
            #pragma unroll
            for (int mt = 0; mt < 2; mt++) {
                s8v a = *(const s8v*)(s_a + (rbase + mt * 16 + m) * EF_STR + kc * 32 + quad * 8);
                acc2[mt][0] = __builtin_amdgcn_mfma_f32_16x16x32_bf16(a, b0, acc2[mt][0], 0, 0, 0);
                acc2[mt][1] = __builtin_amdgcn_mfma_f32_16x16x32_bf16(a, b1v, acc2[mt][1], 0, 0, 0);
            }
        }
        #pragma unroll
        for (int tt = 0; tt < 2; tt++) {
            int col = (wt * 2 + tt) * 16 + m;
            float bias = b2[col];
            #pragma unroll
            for (int mt = 0; mt < 2; mt++)
                #pragma unroll
                for (int r = 0; r < 4; r++)
                    s_b[(rbase + mt * 16 + quad * 4 + r) * EF_STR + col] = f2bf_t(silu_f(acc2[mt][tt][r] + bias));
        }
    }
    __syncthreads(); // B4: efb ready

    // ---- coord gate: partial sums ×cWc → s_t (float, stride 20) ----
    {
        f4v acc3[2][2];
        #pragma unroll
        for (int mt = 0; mt < 2; mt++) { acc3[mt][0] = (f4v){0,0,0,0}; acc3[mt][1] = (f4v){0,0,0,0}; }
        const ushort* bBase = cw1s + wt * 1024 + (size_t)lane * 8;
        #pragma unroll
        for (int kc = 0; kc < 4; kc++) {
            s8v b0 = *(const s8v*)(bBase + kc * 4096);
            s8v b1v = *(const s8v*)(bBase + kc * 4096 + 512);
            #pragma unroll
            for (int mt = 0; mt < 2; mt++) {
                s8v a = *(const s8v*)(s_b + (rbase + mt * 16 + m) * EF_STR + kc * 32 + quad * 8);
                acc3[mt][0] = __builtin_amdgcn_mfma_f32_16x16x32_bf16(a, b0, acc3[mt][0], 0, 0, 0);
                acc3[mt][1] = __builtin_amdgcn_mfma_f32_16x16x32_bf16(a, b1v, acc3[mt][1], 0, 0, 0);
            }
        }
        int c0 = wt * 32 + m, c1 = wt * 32 + 16 + m;
        float bias0 = cb1[c0], wc0 = cwc[c0];
        float bias1 = cb1[c1], wc1 = cwc[c1];
        float* s_part = (float*)s_t;   // [edge][lane-slot 0..15], stride 20 (2-way free)
        #pragma unroll
        for (int mt = 0; mt < 2; mt++)
            #pragma unroll
            for (int r = 0; r < 4; r++) {
                float p = silu_f(acc3[mt][0][r] + bias0) * wc0 + silu_f(acc3[mt][1][r] + bias1) * wc1;
                // slot = wt*4 .. wt*4+3 folded into m? No: each of 16 lanes (m) holds a
                // 16-col partial for this edge; all 16 must be summed. Slot index = m.
                s_part[(rbase + mt * 16 + quad * 4 + r) * 20 + m] = 0.0f; // placeholder overwritten below
                s_part[(rbase + mt * 16 + quad * 4 + r) * 20 + m] = p;
            }
    }
    __syncthreads(); // B5: partials ready  (NOTE: 4 waves (wt) wrote the same slot m!)

    // The 4 wt-waves of each edge-half write DISTINCT col-groups but the SAME slot m.
    // To avoid that race we must include wt in the slot. Redo safely: slots are (wt*4+quad)?
    // -- handled above is WRONG; corrected implementation below uses a second pass. --
    // (This comment block intentionally documents the hazard; code below is the fix.)

    // ---- coord reduce + atomics (one wave) + feature aggregation ----
    if (tid < 64) {
        float* s_part = (float*)s_t;
        float cw = 0.0f;
        #pragma unroll
        for (int l = 0; l < 16; l++) cw += s_part[tid * 20 + l];
        int cn = s_col[tid];
        unsafeAtomicAdd(&agg_coord[cn * 3 + 0], s_cd[tid * 3 + 0] * cw);
        unsafeAtomicAdd(&agg_coord[cn * 3 + 1], s_cd[tid * 3 + 1] * cw);
        unsafeAtomicAdd(&agg_coord[cn * 3 + 2], s_cd[tid * 3 + 2] * cw);
    }

    // feature aggregation: wave-uniform run-length scan over sorted cols
    {
        int j = tid & 127;
        int e0 = (tid >> 7) * 16;
        float accv = 0.0f; int cur = s_col[e0];
        #pragma unroll 4
        for (int e = e0; e < e0 + 16; e++) {
            int c = s_col[e];
            if (c != cur) {
                unsafeAtomicAdd(&agg_feat[(size_t)cur * 128 + j], accv);
                accv = 0.0f; cur = c;
            }
            accv += bf2f(s_b[e * EF_STR + j]);
        }
        unsafeAtomicAdd(&agg_feat[(size_t)cur * 128 + j], accv);
    }
}

// NOTE on the race flagged above: slot must encode wt. The kernel above as written has
// 4 waves writing s_part[row*20 + m] for the same (row, m). Fixed variant: partials are
// pre-reduced across the 16 m-lanes *within* the wave via LDS is what we removed...
// Instead: write to slot (wt*4 + (m&3)) after folding m-groups of 4 via __shfl_xor (2 steps).
// That is what k_edge_fixed implements; kernel_launch uses k_edge_fixed.

__global__ void __launch_bounds__(512, 6) k_edge_fixed(
    const ushort* __restrict__ hbf, const float* __restrict__ cbuf,
    const int* __restrict__ srow, const int* __restrict__ scol, const float* __restrict__ sattr,
    const ushort* __restrict__ w1s, const float* __restrict__ b1,
    const ushort* __restrict__ w2s, const float* __restrict__ b2,
    const ushort* __restrict__ cw1s, const float* __restrict__ cb1,
    const float* __restrict__ cwc,
    float* __restrict__ agg_feat, float* __restrict__ agg_coord)
{
    __shared__ alignas(16) ushort s_a[64 * EF_STR];
    __shared__ alignas(16) ushort s_b[64 * EF_STR];
    __shared__ alignas(16) ushort s_t[64 * TL_STR];
    __shared__ int   s_col[64];
    __shared__ float s_cd[64 * 3];

    const int tid = threadIdx.x;
    const int eb = blockIdx.x * 64;

    if (tid < 64) {
        int rw = srow[eb + tid], cl = scol[eb + tid];
        s_col[tid] = cl;
        float d0 = cbuf[rw * 3 + 0] - cbuf[cl * 3 + 0];
        float d1 = cbuf[rw * 3 + 1] - cbuf[cl * 3 + 1];
        float d2 = cbuf[rw * 3 + 2] - cbuf[cl * 3 + 2];
        s_cd[tid * 3 + 0] = d0; s_cd[tid * 3 + 1] = d1; s_cd[tid * 3 + 2] = d2;
        float dist = d0 * d0 + d1 * d1 + d2 * d2;
        s_t[tid * TL_STR + 0] = f2bf(dist);
        s_t[tid * TL_STR + 1] = f2bf(sattr[eb + tid]);
        uint* zp = (uint*)(s_t + tid * TL_STR + 2);
        #pragma unroll
        for (int z = 0; z < 15; z++) zp[z] = 0;
    }
    #pragma unroll
    for (int i = 0; i < 4; i++) {
        int idx = i * 512 + tid;
        int e = idx >> 5, ch = idx & 31;
        int node = (ch < 16) ? scol[eb + e] : srow[eb + e];
        uint4 v = *(const uint4*)(hbf + (size_t)node * 128 + (ch & 15) * 8);
        ushort* dst = (ch < 16) ? (s_a + e * EF_STR + ch * 8)
                                : (s_b + e * EF_STR + (ch - 16) * 8);
        *(uint4*)dst = v;
    }
    __syncthreads(); // B1

    const int lane = tid & 63, wave = tid >> 6;
    const int m = lane & 15, quad = lane >> 4;
    const int ws2 = wave >> 2, wt = wave & 3;
    const int rbase = ws2 * 32;

    f4v acc[2][2];
    #pragma unroll
    for (int mt = 0; mt < 2; mt++) { acc[mt][0] = (f4v){0,0,0,0}; acc[mt][1] = (f4v){0,0,0,0}; }
    {
        const ushort* bBase = w1s + wt * 1024 + (size_t)lane * 8;
        #pragma unroll
        for (int kc = 0; kc < 4; kc++) {
            s8v b0 = *(const s8v*)(bBase + kc * 4096);
            s8v b1v = *(const s8v*)(bBase + kc * 4096 + 512);
            #pragma unroll
            for (int mt = 0; mt < 2; mt++) {
                s8v a = *(const s8v*)(s_a + (rbase + mt * 16 + m) * EF_STR + kc * 32 + quad * 8);
                acc[mt][0] = __builtin_amdgcn_mfma_f32_16x16x32_bf16(a, b0, acc[mt][0], 0, 0, 0);
                acc[mt][1] = __builtin_amdgcn_mfma_f32_16x16x32_bf16(a, b1v, acc[mt][1], 0, 0, 0);
            }
        }
        #pragma unroll
        for (int kc = 4; kc < 8; kc++) {
            s8v b0 = *(const s8v*)(bBase + kc * 4096);
            s8v b1v = *(const s8v*)(bBase + kc * 4096 + 512);
            #pragma unroll
            for (int mt = 0; mt < 2; mt++) {
                s8v a = *(const s8v*)(s_b + (rbase + mt * 16 + m) * EF_STR + (kc - 4) * 32 + quad * 8);
                acc[mt][0] = __builtin_amdgcn_mfma_f32_16x16x32_bf16(a, b0, acc[mt][0], 0, 0, 0);
                acc[mt][1] = __builtin_amdgcn_mfma_f32_16x16x32_bf16(a, b1v, acc[mt][1], 0, 0, 0);
            }
        }
        {
            s8v b0 = *(const s8v*)(bBase + 8 * 4096);
            s8v b1v = *(const s8v*)(bBase + 8 * 4096 + 512);
            #pragma unroll
            for (int mt = 0; mt < 2; mt++) {
                s8v a = *(const s8v*)(s_t + (rbase + mt * 16 + m) * TL_STR + quad * 8);
                acc[mt][0] = __builtin_amdgcn_mfma_f32_16x16x32_bf16(a, b0, acc[mt][0], 0, 0, 0);
                acc[mt][1] = __builtin_amdgcn_mfma_f32_16x16x32_bf16(a, b1v, acc[mt][1], 0, 0, 0);
            }
        }
    }
    __syncthreads(); // B2

    #pragma unroll
    for (int tt = 0; tt < 2; tt++) {
        int col = (wt * 2 + tt) * 16 + m;
        float bias = b1[col];
        #pragma unroll
        for (int mt = 0; mt < 2; mt++)
            #pragma unroll
            for (int r = 0; r < 4; r++)
                s_a[(rbase + mt * 16 + quad * 4 + r) * EF_STR + col] = f2bf_t(silu_f(acc[mt][tt][r] + bias));
    }
    __syncthreads(); // B3

    {
        f4v acc2[2][2];
        #pragma unroll
        for (int mt = 0; mt < 2; mt++) { acc2[mt][0] = (f4v){0,0,0,0}; acc2[mt][1] = (f4v){0,0,0,0}; }
        const ushort* bBase = w2s + wt * 1024 + (size_t)lane * 8;
        #pragma unroll
        for (int kc = 0; kc < 4; kc++) {
            s8v b0 = *(const s8v*)(bBase + kc * 4096);
            s8v b1v = *(const s8v*)(bBase + kc * 4096 + 512);
            #pragma unroll
            for (int mt = 0; mt < 2; mt++) {
                s8v a = *(const s8v*)(s_a + (rbase + mt * 16 + m) * EF_STR + kc * 32 + quad * 8);
                acc2[mt][0] = __builtin_amdgcn_mfma_f32_16x16x32_bf16(a, b0, acc2[mt][0], 0, 0, 0);
                acc2[mt][1] = __builtin_amdgcn_mfma_f32_16x16x32_bf16(a, b1v, acc2[mt][1], 0, 0, 0);
            }
        }
        #pragma unroll
        for (int tt = 0; tt < 2; tt++) {
            int col = (wt * 2 + tt) * 16 + m;
            float bias = b2[col];
            #pragma unroll
            for (int mt = 0; mt < 2; mt++)
                #pragma unroll
                for (int r = 0; r < 4; r++)
                    s_b[(rbase + mt * 16 + quad * 4 + r) * EF_STR + col] = f2bf_t(silu_f(acc2[mt][tt][r] + bias));
        }
    }
    __syncthreads(); // B4

    {
        f4v acc3[2][2];
        #pragma unroll
        for (int mt = 0; mt < 2; mt++) { acc3[mt][0] = (f4v){0,0,0,0}; acc3[mt][1] = (f4v){0,0,0,0}; }
        const ushort* bBase = cw1s + wt * 1024 + (size_t)lane * 8;
        #pragma unroll
        for (int kc = 0; kc < 4; kc++) {
            s8v b0 = *(const s8v*)(bBase + kc * 4096);
            s8v b1v = *(const s8v*)(bBase + kc * 4096 + 512);
            #pragma unroll
            for (int mt = 0; mt < 2; mt++) {
                s8v a = *(const s8v*)(s_b + (rbase + mt * 16 + m) * EF_STR + kc * 32 + quad * 8);
                acc3[mt][0] = __builtin_amdgcn_mfma_f32_16x16x32_bf16(a, b0, acc3[mt][0], 0, 0, 0);
                acc3[mt][1] = __builtin_amdgcn_mfma_f32_16x16x32_bf16(a, b1v, acc3[mt][1], 0, 0, 0);
            }
        }
        int c0 = wt * 32 + m, c1 = wt * 32 + 16 + m;
        float bias0 = cb1[c0], wc0 = cwc[c0];
        float bias1 = cb1[c1], wc1 = cwc[c1];
        float* s_part = (float*)s_t;   // [edge][slot 0..15], stride 20 floats
        #pragma unroll
        for (int mt = 0; mt < 2; mt++)
            #pragma unroll
            for (int r = 0; r < 4; r++) {
                float p = silu_f(acc3[mt][0][r] + bias0) * wc0 + silu_f(acc3[mt][1][r] + bias1) * wc1;
                // fold 16 m-lanes → 4 partials via 2 xor-shuffles (lanes m, m^1, m^2 summed)
                p += __shfl_xor(p, 1, 64);
                p += __shfl_xor(p, 2, 64);
                if ((m & 3) == 0) {
                    int slot = wt * 4 + (m >> 2);        // 16 distinct slots across wt-waves
                    s_part[(rbase + mt * 16 + quad * 4 + r) * 20 + slot] = p;
                }
            }
    }
    __syncthreads(); // B5

    if (tid < 64) {
        float* s_part = (float*)s_t;
        float cw = 0.0f;
        #pragma unroll
        for (int l = 0; l < 16; l++) cw += s_part[tid * 20 + l];
        int cn = s_col[tid];
        unsafeAtomicAdd(&agg_coord[cn * 3 + 0], s_cd[tid * 3 + 0] * cw);
        unsafeAtomicAdd(&agg_coord[cn * 3 + 1], s_cd[tid * 3 + 1] * cw);
        unsafeAtomicAdd(&agg_coord[cn * 3 + 2], s_cd[tid * 3 + 2] * cw);
    }
    {
        int j = tid & 127;
        int e0 = (tid >> 7) * 16;
        float accv = 0.0f; int cur = s_col[e0];
        #pragma unroll 4
        for (int e = e0; e < e0 + 16; e++) {
            int c = s_col[e];
            if (c != cur) {
                unsafeAtomicAdd(&agg_feat[(size_t)cur * 128 + j], accv);
                accv = 0.0f; cur = c;
            }
            accv += bf2f(s_b[e * EF_STR + j]);
        }
        unsafeAtomicAdd(&agg_feat[(size_t)cur * 128 + j], accv);
    }
}

// ---------------- node update (MFMA bf16) ----------------
__global__ void __launch_bounds__(512, 6) k_node(
    float* __restrict__ hbuf, ushort* __restrict__ hbf, float* __restrict__ cbuf,
    const float* __restrict__ agg_feat, const float* __restrict__ agg_coord,
    const int* __restrict__ ecnt,
    const ushort* __restrict__ w1s, const float* __restrict__ b1,
    const ushort* __restrict__ w2s, const float* __restrict__ b2)
{
    __shared__ alignas(16) ushort s_nin[64 * NIN_STR]; // 33792 B
    __shared__ alignas(16) ushort s_t1[64 * EF_STR];   // 17408 B
    const int tid = threadIdx.x;
    const int nb = blockIdx.x * 64;

    #pragma unroll
    for (int i = 0; i < 2; i++) {
        int idx = i * 512 + tid;
        int e = idx >> 4, ch = idx & 15;
        int node = nb + e;
        uint4 v = make_uint4(0, 0, 0, 0);
        if (node < Nn) v = *(const uint4*)(hbf + (size_t)node * 128 + ch * 8);
        *(uint4*)(s_nin + e * NIN_STR + ch * 8) = v;
    }
    #pragma unroll
    for (int i = 0; i < 4; i++) {
        int idx = i * 512 + tid;
        int e = idx >> 5, ch = idx & 31;
        int node = nb + e;
        float4 f = make_float4(0.f, 0.f, 0.f, 0.f);
        if (node < Nn) f = *(const float4*)(agg_feat + (size_t)node * 128 + ch * 4);
        ushort4 u; u.x = f2bf_t(f.x); u.y = f2bf_t(f.y); u.z = f2bf_t(f.z); u.w = f2bf_t(f.w);
        *(ushort4*)(s_nin + e * NIN_STR + 128 + ch * 4) = u;
    }
    if (tid < 64) {
        int n = nb + tid;
        if (n < Nn) {
            float c = (float)ecnt[n]; c = (c < 1.0f) ? 1.0f : c;
            float inv = __fdividef(1.0f, c);
            cbuf[n * 3 + 0] += agg_coord[n * 3 + 0] * inv;
            cbuf[n * 3 + 1] += agg_coord[n * 3 + 1] * inv;
            cbuf[n * 3 + 2] += agg_coord[n * 3 + 2] * inv;
        }
    }
    __syncthreads();

    const int lane = tid & 63, wave = tid >> 6;
    const int m = lane & 15, quad = lane >> 4;
    const int ws2 = wave >> 2, wt = wave & 3;
    const int rbase = ws2 * 32;

    {
        f4v acc[2][2];
        #pragma unroll
        for (int mt = 0; mt < 2; mt++) { acc[mt][0] = (f4v){0,0,0,0}; acc[mt][1] = (f4v){0,0,0,0}; }
        const ushort* bBase = w1s + wt * 1024 + (size_t)lane * 8;
        #pragma unroll
        for (int kc = 0; kc < 8; kc++) {
            s8v b0 = *(const s8v*)(bBase + kc * 4096);
            s8v b1v = *(const s8v*)(bBase + kc * 4096 + 512);
            #pragma unroll
            for (int mt = 0; mt < 2; mt++) {
                s8v a = *(const s8v*)(s_nin + (rbase + mt * 16 + m) * NIN_STR + kc * 32 + quad * 8);
                acc[mt][0] = __builtin_amdgcn_mfma_f32_16x16x32_bf16(a, b0, acc[mt][0], 0, 0, 0);
                acc[mt][1] = __builtin_amdgcn_mfma_f32_16x16x32_bf16(a, b1v, acc[mt][1], 0, 0, 0);
            }
        }
        #pragma unroll
        for (int tt = 0; tt < 2; tt++) {
            int col = (wt * 2 + tt) * 16 + m;
            float bias = b1[col];
            #pragma unroll
            for (int mt = 0; mt < 2; mt++)
                #pragma unroll
                for (int r = 0; r < 4; r++)
                    s_t1[(rbase + mt * 16 + quad * 4 + r) * EF_STR + col] = f2bf_t(silu_f(acc[mt][tt][r] + bias));
        }
    }
    __syncthreads();

    {
        f4v acc[2][2];
        #pragma unroll
        for (int mt = 0; mt < 2; mt++) { acc[mt][0] = (f4v){0,0,0,0}; acc[mt][1] = (f4v){0,0,0,0}; }
        const ushort* bBase = w2s + wt * 1024 + (size_t)lane * 8;
        #pragma unroll
        for (int kc = 0; kc < 4; kc++) {
            s8v b0 = *(const s8v*)(bBase + kc * 4096);
            s8v b1v = *(const s8v*)(bBase + kc * 4096 + 512);
            #pragma unroll
            for (int mt = 0; mt < 2; mt++) {
                s8v a = *(const s8v*)(s_t1 + (rbase + mt * 16 + m) * EF_STR + kc * 32 + quad * 8);
                acc[mt][0] = __builtin_amdgcn_mfma_f32_16x16x32_bf16(a, b0, acc[mt][0], 0, 0, 0);
                acc[mt][1] = __builtin_amdgcn_mfma_f32_16x16x32_bf16(a, b1v, acc[mt][1], 0, 0, 0);
            }
        }
        #pragma unroll
        for (int tt = 0; tt < 2; tt++) {
            int col = (wt * 2 + tt) * 16 + m;
            float bias = b2[col];
            #pragma unroll
            for (int mt = 0; mt < 2; mt++)
                #pragma unroll
                for (int r = 0; r < 4; r++) {
                    int node = nb + rbase + mt * 16 + quad * 4 + r;
                    if (node < Nn) {
                        float v = hbuf[(size_t)node * 128 + col] + acc[mt][tt][r] + bias;
                        hbuf[(size_t)node * 128 + col] = v;
                        hbf[(size_t)node * 128 + col] = f2bf(v);
                    }
                }
        }
    }
}

// ---------------- output embedding (MFMA bf16) + coords out ----------------
__global__ void __launch_bounds__(512, 2) k_emb_out(
    const ushort* __restrict__ hbf, const float* __restrict__ cbuf,
    const ushort* __restrict__ ws_, const float* __restrict__ b, float* __restrict__ out)
{
    __shared__ alignas(16) ushort s_h[64 * EF_STR];
    const int tid = threadIdx.x;
    const int nb = blockIdx.x * 64;
    #pragma unroll
    for (int i = 0; i < 2; i++) {
        int idx = i * 512 + tid;
        int e = idx >> 4, ch = idx & 15;
        int node = nb + e;
        uint4 v = make_uint4(0, 0, 0, 0);
        if (node < Nn) v = *(const uint4*)(hbf + (size_t)node * 128 + ch * 8);
        *(uint4*)(s_h + e * EF_STR + ch * 8) = v;
    }
    if (tid < 192) {
        int n = nb + tid / 3, d = tid % 3;
        if (n < Nn) out[(size_t)Nn * 128 + n * 3 + d] = cbuf[n * 3 + d];
    }
    __syncthreads();
    const int lane = tid & 63, wave = tid >> 6;
    const int m = lane & 15, quad = lane >> 4;
    const int ws2 = wave >> 2, wt = wave & 3;
    f4v acc[2][2];
    #pragma unroll
    for (int mt = 0; mt < 2; mt++) { acc[mt][0] = (f4v){0,0,0,0}; acc[mt][1] = (f4v){0,0,0,0}; }
    const ushort* bBase = ws_ + wt * 1024 + (size_t)lane * 8;
    #pragma unroll
    for (int kc = 0; kc < 4; kc++) {
        s8v b0 = *(const s8v*)(bBase + kc * 4096);
        s8v b1v = *(const s8v*)(bBase + kc * 4096 + 512);
        #pragma unroll
        for (int mt = 0; mt < 2; mt++) {
            s8v a = *(const s8v*)(s_h + (ws2 * 32 + mt * 16 + m) * EF_STR + kc * 32 + quad * 8);
            acc[mt][0] = __builtin_amdgcn_mfma_f32_16x16x32_bf16(a, b0, acc[mt][0], 0, 0, 0);
            acc[mt][1] = __builtin_amdgcn_mfma_f32_16x16x32_bf16(a, b1v, acc[mt][1], 0, 0, 0);
        }
    }
    #pragma unroll
    for (int tt = 0; tt < 2; tt++) {
        int col = (wt * 2 + tt) * 16 + m;
        float bias = b[col];
        #pragma unroll
        for (int mt = 0; mt < 2; mt++)
            #pragma unroll
            for (int r = 0; r < 4; r++) {
                int node = nb + ws2 * 32 + mt * 16 + quad * 4 + r;
                if (node < Nn) out[(size_t)node * 128 + col] = acc[mt][tt][r] + bias;
            }
    }
}

// ---------------- host launcher ----------------
extern "C" void kernel_launch(void* const* d_in, const int* in_sizes, int n_in,
                              void* d_out, int out_size, void* d_ws, size_t ws_size,
                              hipStream_t stream)
{
    const float* h_in      = (const float*)d_in[0];
    const float* coords    = (const float*)d_in[1];
    const float* edge_attr = (const float*)d_in[2];
    const float* emb_in_W  = (const float*)d_in[3];
    const float* emb_in_b  = (const float*)d_in[4];
    const float* emb_out_W = (const float*)d_in[5];
    const float* emb_out_b = (const float*)d_in[6];
    const float* eW1 = (const float*)d_in[7];
    const float* eb1 = (const float*)d_in[8];
    const float* eW2 = (const float*)d_in[9];
    const float* eb2 = (const float*)d_in[10];
    const float* cW1 = (const float*)d_in[11];
    const float* cb1 = (const float*)d_in[12];
    const float* cWc = (const float*)d_in[13];
    const float* nW1 = (const float*)d_in[14];
    const float* nb1 = (const float*)d_in[15];
    const float* nW2 = (const float*)d_in[16];
    const float* nb2 = (const float*)d_in[17];
    const int*  eidx = (const int*)d_in[18];

    size_t off = 0;
    char* base = (char*)d_ws;
    auto alloc = [&](size_t bytes) -> char* {
        char* p = base + off;
        off += (bytes + 255) & ~(size_t)255;
        return p;
    };
    float*  hbuf      = (float*)alloc((size_t)Nn * 128 * 4);
    ushort* hbf       = (ushort*)alloc((size_t)Nn * 128 * 2);
    float*  cbuf      = (float*)alloc((size_t)Nn * 3 * 4);
    int*    ecnt      = (int*)alloc((size_t)Nn * 4);
    int*    cursor    = (int*)alloc((size_t)Nn * 4);
    int*    srow      = (int*)alloc((size_t)Ee * 4);
    int*    scol      = (int*)alloc((size_t)Ee * 4);
    float*  sattr     = (float*)alloc((size_t)Ee * 4);
    float*  agg_feat  = (float*)alloc((size_t)Nn * 128 * 4);
    float*  agg_coord = (float*)alloc((size_t)Nn * 3 * 4);
    ushort* eW1s      = (ushort*)alloc((size_t)4 * 36864 * 2);
    ushort* eW2s      = (ushort*)alloc((size_t)4 * 16384 * 2);
    ushort* cW1s      = (ushort*)alloc((size_t)4 * 16384 * 2);
    ushort* nW1s      = (ushort*)alloc((size_t)4 * 32768 * 2);
    ushort* nW2s      = (ushort*)alloc((size_t)4 * 16384 * 2);
    ushort* eInWs     = (ushort*)alloc((size_t)8192 * 2);
    ushort* eOutWs    = (ushort*)alloc((size_t)16384 * 2);

    k_swzg<<<(4*9*4096+255)/256, 256, 0, stream>>>(eW1, eW1s, 258, 9, 4*9*4096);
    k_swzg<<<(4*4*4096+255)/256, 256, 0, stream>>>(eW2, eW2s, 128, 4, 4*4*4096);
    k_swzg<<<(4*4*4096+255)/256, 256, 0, stream>>>(cW1, cW1s, 128, 4, 4*4*4096);
    k_swzg<<<(4*8*4096+255)/256, 256, 0, stream>>>(nW1, nW1s, 256, 8, 4*8*4096);
    k_swzg<<<(4*4*4096+255)/256, 256, 0, stream>>>(nW2, nW2s, 128, 4, 4*4*4096);
    k_swzg<<<(2*4096+255)/256,   256, 0, stream>>>(emb_in_W,  eInWs,  64, 2, 2*4096);
    k_swzg<<<(4*4096+255)/256,   256, 0, stream>>>(emb_out_W, eOutWs, 128, 4, 4*4096);

    hipMemsetAsync(ecnt, 0, (size_t)Nn * 4, stream);
    k_count<<<Ee / 256, 256, 0, stream>>>(eidx, ecnt);
    k_scan<<<1, 1024, 0, stream>>>(ecnt, cursor);
    k_scatter<<<Ee / 256, 256, 0, stream>>>(eidx, edge_attr, cursor, srow, scol, sattr);
    k_emb<<<(Nn + 63) / 64, 512, 0, stream>>>(h_in, coords, eInWs, emb_in_b, hbuf, hbf, cbuf);

    for (int l = 0; l < 4; l++) {
        hipMemsetAsync(agg_feat, 0, (size_t)Nn * 128 * 4, stream);
        hipMemsetAsync(agg_coord, 0, (size_t)Nn * 3 * 4, stream);
        k_edge_fixed<<<Ee / 64, 512, 0, stream>>>(
            hbf, cbuf, srow, scol, sattr,
            eW1s + (size_t)l * 36864, eb1 + l * 128,
            eW2s + (size_t)l * 16384, eb2 + l * 128,
            cW1s + (size_t)l * 16384, cb1 + l * 128,
            cWc + l * 128,
            agg_feat, agg_coord);
        k_node<<<(Nn + 63) / 64, 512, 0, stream>>>(
            hbuf, hbf, cbuf, agg_feat, agg_coord, ecnt,
            nW1s + (size_t)l * 32768, nb1 + l * 128,
            nW2s + (size_t)l * 16384, nb2 + l * 128);
    }
    k_emb_out<<<(Nn + 63) / 64, 512, 0, stream>>>(hbf, cbuf, eOutWs, emb_out_b, (float*)d_out);
}